// Round 7
// baseline (2057.543 us; speedup 1.0000x reference)
//
#include <hip/hip_runtime.h>
#include <hip/hip_bf16.h>

#define NN 80000       // nodes
#define NE 160000      // edges (both directions)
#define HALF 80000
#define HID 300
#define NG 1600
#define SCB 256        // scan blocks

typedef __attribute__((ext_vector_type(8))) short bf16x8v;
typedef __attribute__((ext_vector_type(4))) float f32x4v;

// ---------------- helpers ----------------
__device__ __forceinline__ float bf2f_us(unsigned short u) {
    return __uint_as_float(((unsigned int)u) << 16);
}
// native RNE convert: lowers to v_cvt_pk_bf16_f32 on gfx950
__device__ __forceinline__ unsigned short f2bf_us(float f) {
    union { __bf16 b; unsigned short u; } cv;
    cv.b = (__bf16)f;
    return cv.u;
}
__device__ __forceinline__ float ld1(const float* p) { return *p; }
__device__ __forceinline__ float ld1(const unsigned short* p) { return bf2f_us(*p); }
__device__ __forceinline__ float4 ld4(const float* p) { return *(const float4*)p; }
__device__ __forceinline__ float4 ld4(const unsigned short* p) {
    ushort4 u = *(const ushort4*)p;
    return make_float4(bf2f_us(u.x), bf2f_us(u.y), bf2f_us(u.z), bf2f_us(u.w));
}
__device__ __forceinline__ void st4(float* p, float4 v) { *(float4*)p = v; }
__device__ __forceinline__ void st4(unsigned short* p, float4 v) {
    ushort4 u; u.x = f2bf_us(v.x); u.y = f2bf_us(v.y); u.z = f2bf_us(v.z); u.w = f2bf_us(v.w);
    *(ushort4*)p = u;
}
__device__ __forceinline__ int clampi(int v, int lo, int hi) {
    return v < lo ? lo : (v > hi ? hi : v);
}

// ---------------- zero-fill ----------------
__global__ void k_zerof(float* __restrict__ p, int n) {
    int i = blockIdx.x * 256 + threadIdx.x; if (i < n) p[i] = 0.f;
}
__global__ void k_zeroi(int* __restrict__ p, int n) {
    int i = blockIdx.x * 256 + threadIdx.x; if (i < n) p[i] = 0;
}

// ---------------- merged per-conv W split: mp(3 layers) + lin + au in ONE dispatch ----------------
// fragment order per tile t: lane holds B[k=kt*32+quad*8+j][n=ct*16+(lane&15)], j=0..7
__global__ void k_wsplit_conv(const float* __restrict__ Wmp,
                              const float* __restrict__ Wlin, int Klin, int nktlin,
                              const float* __restrict__ Wau, int Kau, int nktau,
                              unsigned short* __restrict__ wh_mp, unsigned short* __restrict__ wl_mp,
                              unsigned short* __restrict__ wh_la, unsigned short* __restrict__ wl_la) {
    const int MP_L = 10 * 19 * 512;   // ushorts per mp layer
    int idx = blockIdx.x * 256 + threadIdx.x;
    int total = 570 + nktlin * 19 + nktau * 19;
    int t = idx >> 6;
    if (t >= total) return;
    int lane = idx & 63;
    const float* W; int Krows, ltile;
    unsigned short *whi, *wlo;
    if (t < 570) {                       // mp: 3 layers x 190 tiles
        int l = t / 190, rem = t - l * 190;
        W = Wmp + l * 90000; Krows = 300; ltile = rem;
        whi = wh_mp + l * MP_L; wlo = wl_mp + l * MP_L;
    } else if (t < 570 + nktlin * 19) {  // lin at la offset 0
        ltile = t - 570; W = Wlin; Krows = Klin;
        whi = wh_la; wlo = wl_la;
    } else {                             // au after lin tiles
        ltile = t - 570 - nktlin * 19; W = Wau; Krows = Kau;
        size_t off = (size_t)nktlin * 19 * 512;
        whi = wh_la + off; wlo = wl_la + off;
    }
    int kt = ltile / 19, ct = ltile - kt * 19;
    int quad = lane >> 4, cr = lane & 15;
    unsigned obase = ((unsigned)ltile * 64u + lane) * 8u;
    for (int j = 0; j < 8; ++j) {
        int k = kt * 32 + quad * 8 + j;
        int n = ct * 16 + cr;
        float v = (k < Krows && n < 300) ? W[(unsigned)k * 300u + n] : 0.f;
        unsigned short hu = f2bf_us(v);
        unsigned short lu = f2bf_us(v - bf2f_us(hu));
        whi[obase + j] = hu;
        wlo[obase + j] = lu;
    }
}

// ---------------- CSR build ----------------
__global__ void k_hist(const int* __restrict__ srcH, const int* __restrict__ dstH, int* __restrict__ deg) {
    int e = blockIdx.x * 256 + threadIdx.x;
    if (e >= NE) return;
    int d = (e < HALF) ? dstH[e] : srcH[e - HALF];
    d = clampi(d, 0, NN - 1);
    atomicAdd(&deg[d], 1);
}
__global__ void k_histg(const int* __restrict__ batch, int* __restrict__ degg) {
    int n = blockIdx.x * 256 + threadIdx.x;
    if (n >= NN) return;
    atomicAdd(&degg[clampi(batch[n], 0, NG - 1)], 1);
}

// ---------------- 3-phase multi-block exclusive scan ----------------
__global__ __launch_bounds__(256) void k_scan_part(const int* __restrict__ deg, int* __restrict__ part, int n) {
    __shared__ int red[256];
    int b = blockIdx.x, t = threadIdx.x;
    int chunk = (n + SCB - 1) / SCB;
    int lo = b * chunk, hi = lo + chunk; if (hi > n) hi = n;
    int s = 0;
    for (int i = lo + t; i < hi; i += 256) s += deg[i];
    red[t] = s;
    __syncthreads();
    for (int off = 128; off > 0; off >>= 1) {
        if (t < off) red[t] += red[t + off];
        __syncthreads();
    }
    if (t == 0) part[b] = red[0];
}
__global__ __launch_bounds__(256) void k_scan_offsets(int* __restrict__ part) {
    __shared__ int sh[256];
    int t = threadIdx.x;
    sh[t] = part[t];
    __syncthreads();
    for (int off = 1; off < 256; off <<= 1) {
        int v = (t >= off) ? sh[t - off] : 0;
        __syncthreads();
        sh[t] += v;
        __syncthreads();
    }
    part[t] = (t == 0) ? 0 : sh[t - 1];
}
__global__ __launch_bounds__(256) void k_scan_apply(const int* __restrict__ deg, const int* __restrict__ part,
                                                    int* __restrict__ start, int* cursor, int n) {
    __shared__ int sh[256];
    int b = blockIdx.x, t = threadIdx.x;
    int chunk = (n + SCB - 1) / SCB;
    int lo = b * chunk, hi = lo + chunk; if (hi > n) hi = n;
    int sub = (chunk + 255) / 256;
    int slo = lo + t * sub, shi = slo + sub;
    if (slo > hi) slo = hi;
    if (shi > hi) shi = hi;
    int s = 0;
    for (int i = slo; i < shi; ++i) s += deg[i];
    sh[t] = s;
    __syncthreads();
    for (int off = 1; off < 256; off <<= 1) {
        int v = (t >= off) ? sh[t - off] : 0;
        __syncthreads();
        sh[t] += v;
        __syncthreads();
    }
    int run = part[b] + sh[t] - s;
    for (int i = slo; i < shi; ++i) {
        int d = deg[i];              // read before aliased cursor write
        start[i] = run;
        if (cursor) cursor[i] = run;
        run += d;
    }
    if (b == SCB - 1 && t == 255) start[n] = run;
}

__global__ void k_fill(const int* __restrict__ srcH, const int* __restrict__ dstH,
                       int* __restrict__ cursor, int* __restrict__ elist) {
    int e = blockIdx.x * 256 + threadIdx.x;
    if (e >= NE) return;
    int d = (e < HALF) ? dstH[e] : srcH[e - HALF];
    d = clampi(d, 0, NN - 1);
    int pos = atomicAdd(&cursor[d], 1);
    if (pos >= 0 && pos < NE) elist[pos] = e;
}

// ---------------- segment sum (pre-mp only): thread per (node, 8-col group) ----------------
// Measured at ~5.4-6 TB/s (roofline) — do not touch.
__global__ __launch_bounds__(256) void k_segsum8(const unsigned short* __restrict__ h,
                                                 const int* __restrict__ elist,
                                                 const int* __restrict__ start,
                                                 unsigned short* __restrict__ inc) {
    int t = blockIdx.x * 256 + threadIdx.x;
    if (t >= NN * 38) return;
    int n = t / 38, q = t - n * 38;
    int c0 = q * 8;
    bool full = (c0 + 8 <= 300);
    int lo = clampi(start[n], 0, NE), hi = clampi(start[n + 1], 0, NE);
    float4 a0 = make_float4(0.f, 0.f, 0.f, 0.f);
    float4 a1 = make_float4(0.f, 0.f, 0.f, 0.f);
    int j = lo;
    for (; j + 2 <= hi; j += 2) {
        unsigned e0 = (unsigned)clampi(elist[j], 0, NE - 1);
        unsigned e1 = (unsigned)clampi(elist[j + 1], 0, NE - 1);
        const unsigned short* r0 = &h[e0 * 300u + c0];
        const unsigned short* r1 = &h[e1 * 300u + c0];
        float4 v0 = ld4(r0);
        float4 w0 = ld4(r1);
        a0.x += v0.x + w0.x; a0.y += v0.y + w0.y; a0.z += v0.z + w0.z; a0.w += v0.w + w0.w;
        if (full) {
            float4 v1 = ld4(r0 + 4);
            float4 w1 = ld4(r1 + 4);
            a1.x += v1.x + w1.x; a1.y += v1.y + w1.y; a1.z += v1.z + w1.z; a1.w += v1.w + w1.w;
        }
    }
    if (j < hi) {
        unsigned e0 = (unsigned)clampi(elist[j], 0, NE - 1);
        const unsigned short* r0 = &h[e0 * 300u + c0];
        float4 v0 = ld4(r0);
        a0.x += v0.x; a0.y += v0.y; a0.z += v0.z; a0.w += v0.w;
        if (full) {
            float4 v1 = ld4(r0 + 4);
            a1.x += v1.x; a1.y += v1.y; a1.z += v1.z; a1.w += v1.w;
        }
    }
    st4(&inc[(unsigned)n * 300u + c0], a0);
    if (full) st4(&inc[(unsigned)n * 300u + c0 + 4], a1);
}

// ================= GEMM core (round 7: 12-wave blocks for lin+mp) =================
// lin/mp: 768 threads = 12 waves over the SAME 64-row x 304-col tile. Wave w owns
// ct = w + 12c (c<2; waves 0-6 get 2 tiles, 7-11 get 1) -> per-lane acc 32 f32 max
// (was 48), weights single-buffered (prefetch dbuf was proven neutral r2) -> live
// ~65 regs. __launch_bounds__(768,6) caps at 85 (margin ~20, no spill risk unlike
// r4's 100-vs-85). 2 blocks x 12 waves = 24 waves/CU vs 20 before. Weight traffic
// per block UNCHANGED (19 tiles/kt still read once per block; same #blocks).
// au keeps the 512-thread r2 form (79 KB LDS would drop it to 1 block at 768).

// ---------------- lin GEMM: h[e] = relu(concat(node_in[src[e]], ea[e]) @ W + b) ----------------
template <int NID, typename TN>
__global__ __launch_bounds__(768, 6) void k_lin_mfma(
        const TN* __restrict__ node_in, const float* __restrict__ ea,
        const int* __restrict__ srcH, const int* __restrict__ dstH,
        const unsigned short* __restrict__ whi, const unsigned short* __restrict__ wlo,
        const float* __restrict__ bias, unsigned short* __restrict__ h) {
    constexpr int K = NID + 14;
    constexpr int KP = (K + 31) & ~31;                    // 160 or 320
    constexpr int NKT = KP / 32;
    constexpr int LDK = (KP + 8 < 312) ? 312 : KP + 8;
    __shared__ unsigned short As[64 * LDK];
    __shared__ int ssrc[64];
    const int tid = threadIdx.x;
    const int lane = tid & 63, wv = tid >> 6;
    const int quad = lane >> 4, cr = lane & 15;
    const int e0 = blockIdx.x * 64;
    if (tid < 64) {
        int e = e0 + tid;
        int s = (e < HALF) ? srcH[e] : dstH[e - HALF];
        ssrc[tid] = clampi(s, 0, NN - 1);
    }
    __syncthreads();
    if constexpr (NID == 300) {
        for (int idx = tid; idx < 64 * 75; idx += 768) {
            int r = idx / 75, q = idx - r * 75;
            *(ushort4*)&As[r * LDK + q * 4] =
                *(const ushort4*)&((const unsigned short*)node_in)[(unsigned)ssrc[r] * 300u + q * 4];
        }
        for (int idx = tid; idx < 64 * (KP - 300); idx += 768) {
            int r = idx / (KP - 300), k = idx - r * (KP - 300);
            int kk = 300 + k;
            float v = (kk < K) ? ea[(unsigned)(e0 + r) * 14u + (kk - 300)] : 0.f;
            As[r * LDK + kk] = f2bf_us(v);
        }
    } else {
        for (int idx = tid; idx < 64 * KP; idx += 768) {
            int r = idx / KP, k = idx - r * KP;
            float v;
            if (k < NID)    v = ld1(&node_in[(unsigned)ssrc[r] * (unsigned)NID + k]);
            else if (k < K) v = ea[(unsigned)(e0 + r) * 14u + (k - NID)];
            else            v = 0.f;
            As[r * LDK + k] = f2bf_us(v);
        }
    }
    __syncthreads();
    f32x4v acc[4][2];
    #pragma unroll
    for (int c = 0; c < 2; ++c) {
        int ct = wv + 12 * c;
        float b = 0.f;
        if (ct < 19) { int col = ct * 16 + cr; if (col < 300) b = bias[col]; }
        #pragma unroll
        for (int rt = 0; rt < 4; ++rt) { f32x4v a = {b, b, b, b}; acc[rt][c] = a; }
    }
    for (int kt = 0; kt < NKT; ++kt) {
        bf16x8v bb[2];
        #pragma unroll
        for (int c = 0; c < 2; ++c) {
            int ct = wv + 12 * c;
            if (ct < 19)
                bb[c] = *(const bf16x8v*)&wlo[((unsigned)(kt * 19 + ct) * 64u + lane) * 8u];
        }
        #pragma unroll
        for (int rt = 0; rt < 4; ++rt) {
            bf16x8v a = *(const bf16x8v*)&As[(rt * 16 + cr) * LDK + kt * 32 + quad * 8];
            #pragma unroll
            for (int c = 0; c < 2; ++c) {
                int ct = wv + 12 * c;
                if (ct >= 19) break;
                acc[rt][c] = __builtin_amdgcn_mfma_f32_16x16x32_bf16(a, bb[c], acc[rt][c], 0, 0, 0);
            }
        }
        #pragma unroll
        for (int c = 0; c < 2; ++c) {
            int ct = wv + 12 * c;
            if (ct < 19)
                bb[c] = *(const bf16x8v*)&whi[((unsigned)(kt * 19 + ct) * 64u + lane) * 8u];
        }
        #pragma unroll
        for (int rt = 0; rt < 4; ++rt) {
            bf16x8v a = *(const bf16x8v*)&As[(rt * 16 + cr) * LDK + kt * 32 + quad * 8];
            #pragma unroll
            for (int c = 0; c < 2; ++c) {
                int ct = wv + 12 * c;
                if (ct >= 19) break;
                acc[rt][c] = __builtin_amdgcn_mfma_f32_16x16x32_bf16(a, bb[c], acc[rt][c], 0, 0, 0);
            }
        }
    }
    __syncthreads();
    #pragma unroll
    for (int c = 0; c < 2; ++c) {
        int ct = wv + 12 * c;
        if (ct >= 19) break;
        int col = ct * 16 + cr;
        if (col >= 300) continue;
        #pragma unroll
        for (int rt = 0; rt < 4; ++rt)
            #pragma unroll
            for (int r = 0; r < 4; ++r)
                As[(rt * 16 + quad * 4 + r) * LDK + col] = f2bf_us(fmaxf(acc[rt][c][r], 0.f));
    }
    __syncthreads();
    for (int idx = tid; idx < 64 * 75; idx += 768) {
        int r = idx / 75, q = idx - r * 75;
        *(ushort4*)&h[(unsigned)(e0 + r) * 300u + q * 4] = *(const ushort4*)&As[r * LDK + q * 4];
    }
}

// ---------------- au GEMM (segsum FUSED): out[n] = (relu?)(concat(node_in[n], segsum_h[n]) @ W + b) ----
// UNCHANGED from the proven round-2 form (512 threads, 8 waves, prefetch dbuf).
template <int NID, typename TN, bool RELU>
__global__ __launch_bounds__(512, 4) void k_au_mfma(
        const TN* __restrict__ node_in, const unsigned short* __restrict__ h,
        const int* __restrict__ elist, const int* __restrict__ start,
        const unsigned short* __restrict__ whi, const unsigned short* __restrict__ wlo,
        const float* __restrict__ bias, unsigned short* __restrict__ out_rows) {
    constexpr int K = NID + 300;
    constexpr int KP = (K + 31) & ~31;     // 448 or 608
    constexpr int NKT = KP / 32;
    constexpr int LDK = KP + 8;            // 456 / 616
    __shared__ unsigned short As[64 * LDK];
    const int tid = threadIdx.x;
    const int lane = tid & 63, wv = tid >> 6;
    const int quad = lane >> 4, cr = lane & 15;
    const int n0 = blockIdx.x * 64;
    // node part: cols [0, NID)
    if constexpr (NID == 300) {
        for (int idx = tid; idx < 64 * 75; idx += 512) {
            int r = idx / 75, q = idx - r * 75;
            *(ushort4*)&As[r * LDK + q * 4] =
                *(const ushort4*)&((const unsigned short*)node_in)[(unsigned)(n0 + r) * 300u + q * 4];
        }
    } else {
        // contiguous 64-row fp32 block: flat aligned float4 copy (64*NID divisible by 4 for NID=133)
        const float* xb = (const float*)node_in + (size_t)n0 * NID;
        for (int f4 = tid; f4 < (64 * NID) / 4; f4 += 512) {
            float4 v = *(const float4*)&xb[f4 * 4];
            int f = f4 * 4;
            float vv[4] = {v.x, v.y, v.z, v.w};
            #pragma unroll
            for (int i = 0; i < 4; ++i) {
                int fi = f + i;
                int r = fi / NID, k = fi - r * NID;
                As[r * LDK + k] = f2bf_us(vv[i]);
            }
        }
    }
    // fused segment-sum gather (2-way unrolled): cols [NID, NID+300)
    for (int idx = tid; idx < 64 * 75; idx += 512) {
        int r = idx / 75, q = idx - r * 75;
        int n = n0 + r;
        int lo = clampi(start[n], 0, NE), hi = clampi(start[n + 1], 0, NE);
        float4 acc = make_float4(0.f, 0.f, 0.f, 0.f);
        int j = lo;
        for (; j + 2 <= hi; j += 2) {
            unsigned ei0 = (unsigned)clampi(elist[j], 0, NE - 1);
            unsigned ei1 = (unsigned)clampi(elist[j + 1], 0, NE - 1);
            float4 v0 = ld4(&h[ei0 * 300u + q * 4]);
            float4 v1 = ld4(&h[ei1 * 300u + q * 4]);
            acc.x += v0.x; acc.y += v0.y; acc.z += v0.z; acc.w += v0.w;
            acc.x += v1.x; acc.y += v1.y; acc.z += v1.z; acc.w += v1.w;
        }
        if (j < hi) {
            unsigned ei0 = (unsigned)clampi(elist[j], 0, NE - 1);
            float4 v0 = ld4(&h[ei0 * 300u + q * 4]);
            acc.x += v0.x; acc.y += v0.y; acc.z += v0.z; acc.w += v0.w;
        }
        unsigned short* dst = &As[r * LDK + NID + q * 4];
        dst[0] = f2bf_us(acc.x); dst[1] = f2bf_us(acc.y);
        dst[2] = f2bf_us(acc.z); dst[3] = f2bf_us(acc.w);
    }
    // pad: cols [NID+300, KP)
    constexpr int PAD = KP - NID - 300;
    for (int idx = tid; idx < 64 * PAD; idx += 512) {
        int r = idx / PAD, k = idx - r * PAD;
        As[r * LDK + NID + 300 + k] = 0;
    }
    __syncthreads();
    f32x4v acc[4][3];
    #pragma unroll
    for (int c = 0; c < 3; ++c) {
        int ct = wv + 8 * c;
        float b = 0.f;
        if (ct < 19) { int col = ct * 16 + cr; if (col < 300) b = bias[col]; }
        #pragma unroll
        for (int rt = 0; rt < 4; ++rt) { f32x4v a = {b, b, b, b}; acc[rt][c] = a; }
    }
    // software-pipelined K-loop (weight prefetch, register double-buffer)
    bf16x8v pbhi[2][3], pblo[2][3];
    #pragma unroll
    for (int c = 0; c < 3; ++c) {
        int ct = wv + 8 * c;
        if (ct < 19) {
            unsigned base = ((unsigned)ct * 64u + lane) * 8u;
            pbhi[0][c] = *(const bf16x8v*)&whi[base];
            pblo[0][c] = *(const bf16x8v*)&wlo[base];
        }
    }
    #pragma unroll
    for (int kt = 0; kt < NKT; ++kt) {
        const int cur = kt & 1, nxt = cur ^ 1;
        if (kt + 1 < NKT) {
            #pragma unroll
            for (int c = 0; c < 3; ++c) {
                int ct = wv + 8 * c;
                if (ct < 19) {
                    unsigned base = ((unsigned)((kt + 1) * 19 + ct) * 64u + lane) * 8u;
                    pbhi[nxt][c] = *(const bf16x8v*)&whi[base];
                    pblo[nxt][c] = *(const bf16x8v*)&wlo[base];
                }
            }
        }
        #pragma unroll
        for (int rt = 0; rt < 4; ++rt) {
            bf16x8v a = *(const bf16x8v*)&As[(rt * 16 + cr) * LDK + kt * 32 + quad * 8];
            #pragma unroll
            for (int c = 0; c < 3; ++c) {
                int ct = wv + 8 * c;
                if (ct >= 19) break;
                acc[rt][c] = __builtin_amdgcn_mfma_f32_16x16x32_bf16(a, pblo[cur][c], acc[rt][c], 0, 0, 0);
                acc[rt][c] = __builtin_amdgcn_mfma_f32_16x16x32_bf16(a, pbhi[cur][c], acc[rt][c], 0, 0, 0);
            }
        }
    }
    __syncthreads();
    #pragma unroll
    for (int c = 0; c < 3; ++c) {
        int ct = wv + 8 * c;
        if (ct >= 19) break;
        int col = ct * 16 + cr;
        if (col >= 300) continue;
        #pragma unroll
        for (int rt = 0; rt < 4; ++rt)
            #pragma unroll
            for (int r = 0; r < 4; ++r) {
                float v = acc[rt][c][r];
                As[(rt * 16 + quad * 4 + r) * LDK + col] = f2bf_us(RELU ? fmaxf(v, 0.f) : v);
            }
    }
    __syncthreads();
    for (int idx = tid; idx < 64 * 75; idx += 512) {
        int r = idx / 75, q = idx - r * 75;
        *(ushort4*)&out_rows[(unsigned)(n0 + r) * 300u + q * 4] = *(const ushort4*)&As[r * LDK + q * 4];
    }
}

// ---------------- mp GEMM: h[e] = relu(h[e] + (inc[src[e]] - h[rev(e)]) @ W + b) ----------------
// 64 rows = 32 pairs / block. Operand (inc[src]-h[pair]) staged directly from global
// in one pass; +h[e]+bias applied in the EPILOGUE from global (round-1 form, 116us <
// round-6 acc-init's 121us). 12 waves, single-buffered weights.
__global__ __launch_bounds__(768, 6) void k_mp_mfma(
        unsigned short* __restrict__ h, const unsigned short* __restrict__ inc,
        const int* __restrict__ srcH, const int* __restrict__ dstH,
        const unsigned short* __restrict__ whi, const unsigned short* __restrict__ wlo,
        const float* __restrict__ bias) {
    constexpr int LDK = 328;
    __shared__ unsigned short Hs[64 * LDK];
    __shared__ int ssrc[64];
    const int tid = threadIdx.x;
    const int lane = tid & 63, wv = tid >> 6;
    const int quad = lane >> 4, cr = lane & 15;
    const int p0 = blockIdx.x * 32;
    if (tid < 64) {
        int r = tid;
        int e = (r < 32) ? (p0 + r) : (p0 + r - 32 + HALF);
        int s = (e < HALF) ? srcH[e] : dstH[e - HALF];
        ssrc[r] = clampi(s, 0, NN - 1);
    }
    __syncthreads();
    // single-pass operand staging: Hs[r] = inc[src[e_r]] - h[pair(e_r)], zero-pad to KP=320
    for (int idx = tid; idx < 64 * 80; idx += 768) {
        int r = idx / 80, q = idx - r * 80;
        int col = q * 4;
        if (col < 300) {
            unsigned ep = (r < 32) ? (unsigned)(p0 + r + HALF) : (unsigned)(p0 + r - 32);
            float4 hp = ld4(&h[ep * 300u + col]);
            float4 iv = ld4(&inc[(unsigned)ssrc[r] * 300u + col]);
            st4(&Hs[r * LDK + col],
                make_float4(iv.x - hp.x, iv.y - hp.y, iv.z - hp.z, iv.w - hp.w));
        } else {
            *(ushort4*)&Hs[r * LDK + col] = make_ushort4(0, 0, 0, 0);
        }
    }
    __syncthreads();
    f32x4v acc[4][2];
    #pragma unroll
    for (int c = 0; c < 2; ++c)
        #pragma unroll
        for (int rt = 0; rt < 4; ++rt) {
            f32x4v a = {0.f, 0.f, 0.f, 0.f};
            acc[rt][c] = a;
        }
    for (int kt = 0; kt < 10; ++kt) {
        bf16x8v bb[2];
        #pragma unroll
        for (int c = 0; c < 2; ++c) {
            int ct = wv + 12 * c;
            if (ct < 19)
                bb[c] = *(const bf16x8v*)&wlo[((unsigned)(kt * 19 + ct) * 64u + lane) * 8u];
        }
        #pragma unroll
        for (int rt = 0; rt < 4; ++rt) {
            bf16x8v a = *(const bf16x8v*)&Hs[(rt * 16 + cr) * LDK + kt * 32 + quad * 8];
            #pragma unroll
            for (int c = 0; c < 2; ++c) {
                int ct = wv + 12 * c;
                if (ct >= 19) break;
                acc[rt][c] = __builtin_amdgcn_mfma_f32_16x16x32_bf16(a, bb[c], acc[rt][c], 0, 0, 0);
            }
        }
        #pragma unroll
        for (int c = 0; c < 2; ++c) {
            int ct = wv + 12 * c;
            if (ct < 19)
                bb[c] = *(const bf16x8v*)&whi[((unsigned)(kt * 19 + ct) * 64u + lane) * 8u];
        }
        #pragma unroll
        for (int rt = 0; rt < 4; ++rt) {
            bf16x8v a = *(const bf16x8v*)&Hs[(rt * 16 + cr) * LDK + kt * 32 + quad * 8];
            #pragma unroll
            for (int c = 0; c < 2; ++c) {
                int ct = wv + 12 * c;
                if (ct >= 19) break;
                acc[rt][c] = __builtin_amdgcn_mfma_f32_16x16x32_bf16(a, bb[c], acc[rt][c], 0, 0, 0);
            }
        }
    }
    __syncthreads();   // all GEMM reads of Hs done before epilogue overwrites
    #pragma unroll
    for (int c = 0; c < 2; ++c) {
        int ct = wv + 12 * c;
        if (ct >= 19) break;
        int col = ct * 16 + cr;
        if (col >= 300) continue;
        float bv = bias[col];
        #pragma unroll
        for (int rt = 0; rt < 4; ++rt)
            #pragma unroll
            for (int r = 0; r < 4; ++r) {
                int row = rt * 16 + quad * 4 + r;
                unsigned e = (row < 32) ? (unsigned)(p0 + row) : (unsigned)(p0 + row - 32 + HALF);
                float hv = bf2f_us(h[e * 300u + col]);   // L1/L2-hot own row
                Hs[row * LDK + col] = f2bf_us(fmaxf(acc[rt][c][r] + bv + hv, 0.f));
            }
    }
    __syncthreads();
    for (int idx = tid; idx < 64 * 75; idx += 768) {
        int r = idx / 75, q = idx - r * 75;
        unsigned e = (r < 32) ? (unsigned)(p0 + r) : (unsigned)(p0 + r - 32 + HALF);
        *(ushort4*)&h[e * 300u + q * 4] = *(const ushort4*)&Hs[r * LDK + q * 4];
    }
}

// ---------------- pooling (bf16 rows) + reparam ----------------
__global__ __launch_bounds__(320) void k_pool(const unsigned short* __restrict__ rows,
                                              const float* __restrict__ wat,
                                              const int* __restrict__ gs, float* __restrict__ outg) {
    int g = blockIdx.x, c = threadIdx.x;
    if (c >= 300) return;
    int lo = clampi(gs[g], 0, NN), hi = clampi(gs[g + 1], 0, NN);
    float acc = 0.f;
    for (int n = lo; n < hi; ++n)
        acc += bf2f_us(rows[(unsigned)n * 300u + c]) * wat[n];
    float cn = fmaxf((float)(hi - lo), 1.f);
    outg[g * 300 + c] = acc / cn;
}
__global__ __launch_bounds__(320) void k_final(const float* __restrict__ mu_g, const float* __restrict__ lv_g,
                                               const float* __restrict__ eps, float* __restrict__ out) {
    int g = blockIdx.x, c = threadIdx.x;
    if (c >= 300) return;
    out[g * 300 + c] = mu_g[g * 300 + c] + expf(0.5f * lv_g[g * 300 + c]) * eps[g * 300 + c];
}

extern "C" void kernel_launch(void* const* d_in, const int* in_sizes, int n_in,
                              void* d_out, int out_size, void* d_ws, size_t ws_size,
                              hipStream_t stream) {
    float* outp = (float*)d_out;

    const size_t NEED = 199500000ull;   // carve ~199.43 MB; ws proven >= 200,000,000
    if (ws_size < NEED) {
        k_zerof<<<(out_size + 255) / 256, 256, 0, stream>>>(outp, out_size);
        return;
    }

    const float* x   = (const float*)d_in[0];
    const float* ea  = (const float*)d_in[1];
    const float* wat = (const float*)d_in[2];
    const float* eps = (const float*)d_in[3];
    const int* srcH  = (const int*)d_in[4];
    const int* dstH  = (const int*)d_in[5];
    const int* batch = (const int*)d_in[6];
    const float* w_t_lin  = (const float*)d_in[7];
    const float* b_t_lin  = (const float*)d_in[8];
    const float* w_t_mp   = (const float*)d_in[9];
    const float* b_t_mp   = (const float*)d_in[10];
    const float* w_t_au   = (const float*)d_in[11];
    const float* b_t_au   = (const float*)d_in[12];
    const float* w_mu_lin = (const float*)d_in[13];
    const float* b_mu_lin = (const float*)d_in[14];
    const float* w_mu_mp  = (const float*)d_in[15];
    const float* b_mu_mp  = (const float*)d_in[16];
    const float* w_mu_au  = (const float*)d_in[17];
    const float* b_mu_au  = (const float*)d_in[18];
    const float* w_lv_lin = (const float*)d_in[19];
    const float* b_lv_lin = (const float*)d_in[20];
    const float* w_lv_mp  = (const float*)d_in[21];
    const float* b_lv_mp  = (const float*)d_in[22];
    const float* w_lv_au  = (const float*)d_in[23];
    const float* b_lv_au  = (const float*)d_in[24];

    char* p = (char*)d_ws;
    auto alloc = [&](size_t nbytes) { char* q = p; p += (nbytes + 255) & ~(size_t)255; return q; };
    unsigned short* h   = (unsigned short*)alloc((size_t)NE * 300 * 2);   // 96 MB
    unsigned short* inc = (unsigned short*)alloc((size_t)NN * 300 * 2);   // 48 MB; dead during au -> reused as rows
    unsigned short* sh  = (unsigned short*)alloc((size_t)NN * 300 * 2);   // 48 MB
    const size_t MPU = (size_t)3 * 10 * 19 * 512;   // mp tables (ushorts)
    unsigned short* wh_mp = (unsigned short*)alloc(MPU * 2);
    unsigned short* wl_mp = (unsigned short*)alloc(MPU * 2);
    const size_t LAU = (size_t)29 * 19 * 512;       // lin+au tables
    unsigned short* wh_la = (unsigned short*)alloc(LAU * 2);
    unsigned short* wl_la = (unsigned short*)alloc(LAU * 2);
    float* mu_g = (float*)alloc((size_t)NG * 300 * 4);
    float* lv_g = (float*)alloc((size_t)NG * 300 * 4);
    int* deg    = (int*)alloc(NN * 4);               // reused as cursor (alias-safe)
    int* startA = (int*)alloc((NN + 1) * 4);
    int* elist  = (int*)alloc(NE * 4);
    int* degg   = (int*)alloc(NG * 4);
    int* gs     = (int*)alloc((NG + 1) * 4);
    int* part   = (int*)alloc(SCB * 4);

    // ---- CSR (incoming by dst), multi-block scan; cursor aliases deg ----
    k_zeroi<<<(NN + 255) / 256, 256, 0, stream>>>(deg, NN);
    k_hist<<<(NE + 255) / 256, 256, 0, stream>>>(srcH, dstH, deg);
    k_scan_part<<<SCB, 256, 0, stream>>>(deg, part, NN);
    k_scan_offsets<<<1, 256, 0, stream>>>(part);
    k_scan_apply<<<SCB, 256, 0, stream>>>(deg, part, startA, deg, NN);
    k_fill<<<(NE + 255) / 256, 256, 0, stream>>>(srcH, dstH, deg, elist);
    // ---- graph-CSR over sorted batch ----
    k_zeroi<<<(NG + 255) / 256, 256, 0, stream>>>(degg, NG);
    k_histg<<<(NN + 255) / 256, 256, 0, stream>>>(batch, degg);
    k_scan_part<<<SCB, 256, 0, stream>>>(degg, part, NG);
    k_scan_offsets<<<1, 256, 0, stream>>>(part);
    k_scan_apply<<<SCB, 256, 0, stream>>>(degg, part, gs, (int*)nullptr, NG);

    const int SSG = (NN * 38 + 255) / 256;
    const size_t MP_L = (size_t)10 * 19 * 512;      // ushorts per mp layer
    unsigned short* rows = inc;                      // au output aliases inc (dead during au)
    auto wsplit_conv = [&](const float* Wmp, const float* Wlin, int Klin, int nktlin,
                           const float* Wau, int Kau, int nktau) {
        int total = 570 + nktlin * 19 + nktau * 19;
        k_wsplit_conv<<<(total * 64 + 255) / 256, 256, 0, stream>>>(
            Wmp, Wlin, Klin, nktlin, Wau, Kau, nktau, wh_mp, wl_mp, wh_la, wl_la);
    };

    // ================= conv t =================
    wsplit_conv(w_t_mp, w_t_lin, 147, 5, w_t_au, 433, 14);
    const size_t AU_T = (size_t)5 * 19 * 512;
    k_lin_mfma<133, float><<<NE / 64, 768, 0, stream>>>(x, ea, srcH, dstH, wh_la, wl_la, b_t_lin, h);
    for (int i = 0; i < 3; ++i) {
        k_segsum8<<<SSG, 256, 0, stream>>>(h, elist, startA, inc);
        k_mp_mfma<<<HALF / 32, 768, 0, stream>>>(h, inc, srcH, dstH,
                                                 wh_mp + i * MP_L, wl_mp + i * MP_L, b_t_mp + i * 300);
    }
    k_au_mfma<133, float, true><<<NN / 64, 512, 0, stream>>>(x, h, elist, startA,
                                                             wh_la + AU_T, wl_la + AU_T, b_t_au, sh);

    // ================= conv mu =================
    wsplit_conv(w_mu_mp, w_mu_lin, 314, 10, w_mu_au, 600, 19);
    const size_t AU_MU = (size_t)10 * 19 * 512;
    k_lin_mfma<300, unsigned short><<<NE / 64, 768, 0, stream>>>(sh, ea, srcH, dstH, wh_la, wl_la, b_mu_lin, h);
    for (int i = 0; i < 3; ++i) {
        k_segsum8<<<SSG, 256, 0, stream>>>(h, elist, startA, inc);
        k_mp_mfma<<<HALF / 32, 768, 0, stream>>>(h, inc, srcH, dstH,
                                                 wh_mp + i * MP_L, wl_mp + i * MP_L, b_mu_mp + i * 300);
    }
    k_au_mfma<300, unsigned short, false><<<NN / 64, 512, 0, stream>>>(sh, h, elist, startA,
                                                                       wh_la + AU_MU, wl_la + AU_MU, b_mu_au, rows);
    k_pool<<<NG, 320, 0, stream>>>(rows, wat, gs, mu_g);

    // ================= conv lv =================
    wsplit_conv(w_lv_mp, w_lv_lin, 314, 10, w_lv_au, 600, 19);
    k_lin_mfma<300, unsigned short><<<NE / 64, 768, 0, stream>>>(sh, ea, srcH, dstH, wh_la, wl_la, b_lv_lin, h);
    for (int i = 0; i < 3; ++i) {
        k_segsum8<<<SSG, 256, 0, stream>>>(h, elist, startA, inc);
        k_mp_mfma<<<HALF / 32, 768, 0, stream>>>(h, inc, srcH, dstH,
                                                 wh_mp + i * MP_L, wl_mp + i * MP_L, b_lv_mp + i * 300);
    }
    k_au_mfma<300, unsigned short, false><<<NN / 64, 512, 0, stream>>>(sh, h, elist, startA,
                                                                       wh_la + AU_MU, wl_la + AU_MU, b_lv_au, rows);
    k_pool<<<NG, 320, 0, stream>>>(rows, wat, gs, lv_g);

    // ---- reparam ----
    k_final<<<NG, 320, 0, stream>>>(mu_g, lv_g, eps, outp);
}

// Round 8
// 2016.799 us; speedup vs baseline: 1.0202x; 1.0202x over previous
//
#include <hip/hip_runtime.h>
#include <hip/hip_bf16.h>

#define NN 80000       // nodes
#define NE 160000      // edges (both directions)
#define HALF 80000
#define HID 300
#define NG 1600
#define SCB 256        // scan blocks

typedef __attribute__((ext_vector_type(8))) short bf16x8v;
typedef __attribute__((ext_vector_type(4))) float f32x4v;

// ---------------- helpers ----------------
__device__ __forceinline__ float bf2f_us(unsigned short u) {
    return __uint_as_float(((unsigned int)u) << 16);
}
// native RNE convert: lowers to v_cvt_pk_bf16_f32 on gfx950
__device__ __forceinline__ unsigned short f2bf_us(float f) {
    union { __bf16 b; unsigned short u; } cv;
    cv.b = (__bf16)f;
    return cv.u;
}
__device__ __forceinline__ float ld1(const float* p) { return *p; }
__device__ __forceinline__ float ld1(const unsigned short* p) { return bf2f_us(*p); }
__device__ __forceinline__ float4 ld4(const float* p) { return *(const float4*)p; }
__device__ __forceinline__ float4 ld4(const unsigned short* p) {
    ushort4 u = *(const ushort4*)p;
    return make_float4(bf2f_us(u.x), bf2f_us(u.y), bf2f_us(u.z), bf2f_us(u.w));
}
__device__ __forceinline__ void st4(float* p, float4 v) { *(float4*)p = v; }
__device__ __forceinline__ void st4(unsigned short* p, float4 v) {
    ushort4 u; u.x = f2bf_us(v.x); u.y = f2bf_us(v.y); u.z = f2bf_us(v.z); u.w = f2bf_us(v.w);
    *(ushort4*)p = u;
}
__device__ __forceinline__ int clampi(int v, int lo, int hi) {
    return v < lo ? lo : (v > hi ? hi : v);
}

// ---------------- zero-fill ----------------
__global__ void k_zerof(float* __restrict__ p, int n) {
    int i = blockIdx.x * 256 + threadIdx.x; if (i < n) p[i] = 0.f;
}
__global__ void k_zeroi(int* __restrict__ p, int n) {
    int i = blockIdx.x * 256 + threadIdx.x; if (i < n) p[i] = 0;
}

// ---------------- merged per-conv W split: mp(3 layers) + lin + au in ONE dispatch ----------------
// fragment order per tile t: lane holds B[k=kt*32+quad*8+j][n=ct*16+(lane&15)], j=0..7
__global__ void k_wsplit_conv(const float* __restrict__ Wmp,
                              const float* __restrict__ Wlin, int Klin, int nktlin,
                              const float* __restrict__ Wau, int Kau, int nktau,
                              unsigned short* __restrict__ wh_mp, unsigned short* __restrict__ wl_mp,
                              unsigned short* __restrict__ wh_la, unsigned short* __restrict__ wl_la) {
    const int MP_L = 10 * 19 * 512;   // ushorts per mp layer
    int idx = blockIdx.x * 256 + threadIdx.x;
    int total = 570 + nktlin * 19 + nktau * 19;
    int t = idx >> 6;
    if (t >= total) return;
    int lane = idx & 63;
    const float* W; int Krows, ltile;
    unsigned short *whi, *wlo;
    if (t < 570) {                       // mp: 3 layers x 190 tiles
        int l = t / 190, rem = t - l * 190;
        W = Wmp + l * 90000; Krows = 300; ltile = rem;
        whi = wh_mp + l * MP_L; wlo = wl_mp + l * MP_L;
    } else if (t < 570 + nktlin * 19) {  // lin at la offset 0
        ltile = t - 570; W = Wlin; Krows = Klin;
        whi = wh_la; wlo = wl_la;
    } else {                             // au after lin tiles
        ltile = t - 570 - nktlin * 19; W = Wau; Krows = Kau;
        size_t off = (size_t)nktlin * 19 * 512;
        whi = wh_la + off; wlo = wl_la + off;
    }
    int kt = ltile / 19, ct = ltile - kt * 19;
    int quad = lane >> 4, cr = lane & 15;
    unsigned obase = ((unsigned)ltile * 64u + lane) * 8u;
    for (int j = 0; j < 8; ++j) {
        int k = kt * 32 + quad * 8 + j;
        int n = ct * 16 + cr;
        float v = (k < Krows && n < 300) ? W[(unsigned)k * 300u + n] : 0.f;
        unsigned short hu = f2bf_us(v);
        unsigned short lu = f2bf_us(v - bf2f_us(hu));
        whi[obase + j] = hu;
        wlo[obase + j] = lu;
    }
}

// ---------------- CSR build ----------------
__global__ void k_hist(const int* __restrict__ srcH, const int* __restrict__ dstH, int* __restrict__ deg) {
    int e = blockIdx.x * 256 + threadIdx.x;
    if (e >= NE) return;
    int d = (e < HALF) ? dstH[e] : srcH[e - HALF];
    d = clampi(d, 0, NN - 1);
    atomicAdd(&deg[d], 1);
}
__global__ void k_histg(const int* __restrict__ batch, int* __restrict__ degg) {
    int n = blockIdx.x * 256 + threadIdx.x;
    if (n >= NN) return;
    atomicAdd(&degg[clampi(batch[n], 0, NG - 1)], 1);
}

// ---------------- 3-phase multi-block exclusive scan ----------------
__global__ __launch_bounds__(256) void k_scan_part(const int* __restrict__ deg, int* __restrict__ part, int n) {
    __shared__ int red[256];
    int b = blockIdx.x, t = threadIdx.x;
    int chunk = (n + SCB - 1) / SCB;
    int lo = b * chunk, hi = lo + chunk; if (hi > n) hi = n;
    int s = 0;
    for (int i = lo + t; i < hi; i += 256) s += deg[i];
    red[t] = s;
    __syncthreads();
    for (int off = 128; off > 0; off >>= 1) {
        if (t < off) red[t] += red[t + off];
        __syncthreads();
    }
    if (t == 0) part[b] = red[0];
}
__global__ __launch_bounds__(256) void k_scan_offsets(int* __restrict__ part) {
    __shared__ int sh[256];
    int t = threadIdx.x;
    sh[t] = part[t];
    __syncthreads();
    for (int off = 1; off < 256; off <<= 1) {
        int v = (t >= off) ? sh[t - off] : 0;
        __syncthreads();
        sh[t] += v;
        __syncthreads();
    }
    part[t] = (t == 0) ? 0 : sh[t - 1];
}
__global__ __launch_bounds__(256) void k_scan_apply(const int* __restrict__ deg, const int* __restrict__ part,
                                                    int* __restrict__ start, int* cursor, int n) {
    __shared__ int sh[256];
    int b = blockIdx.x, t = threadIdx.x;
    int chunk = (n + SCB - 1) / SCB;
    int lo = b * chunk, hi = lo + chunk; if (hi > n) hi = n;
    int sub = (chunk + 255) / 256;
    int slo = lo + t * sub, shi = slo + sub;
    if (slo > hi) slo = hi;
    if (shi > hi) shi = hi;
    int s = 0;
    for (int i = slo; i < shi; ++i) s += deg[i];
    sh[t] = s;
    __syncthreads();
    for (int off = 1; off < 256; off <<= 1) {
        int v = (t >= off) ? sh[t - off] : 0;
        __syncthreads();
        sh[t] += v;
        __syncthreads();
    }
    int run = part[b] + sh[t] - s;
    for (int i = slo; i < shi; ++i) {
        int d = deg[i];              // read before aliased cursor write
        start[i] = run;
        if (cursor) cursor[i] = run;
        run += d;
    }
    if (b == SCB - 1 && t == 255) start[n] = run;
}

__global__ void k_fill(const int* __restrict__ srcH, const int* __restrict__ dstH,
                       int* __restrict__ cursor, int* __restrict__ elist) {
    int e = blockIdx.x * 256 + threadIdx.x;
    if (e >= NE) return;
    int d = (e < HALF) ? dstH[e] : srcH[e - HALF];
    d = clampi(d, 0, NN - 1);
    int pos = atomicAdd(&cursor[d], 1);
    if (pos >= 0 && pos < NE) elist[pos] = e;
}

// ---------------- segment sum: thread per (node, 8-col group) ----------------
// Measured at ~5.4-6 TB/s (roofline for this gather). Now also feeds the de-fused au.
__global__ __launch_bounds__(256) void k_segsum8(const unsigned short* __restrict__ h,
                                                 const int* __restrict__ elist,
                                                 const int* __restrict__ start,
                                                 unsigned short* __restrict__ inc) {
    int t = blockIdx.x * 256 + threadIdx.x;
    if (t >= NN * 38) return;
    int n = t / 38, q = t - n * 38;
    int c0 = q * 8;
    bool full = (c0 + 8 <= 300);
    int lo = clampi(start[n], 0, NE), hi = clampi(start[n + 1], 0, NE);
    float4 a0 = make_float4(0.f, 0.f, 0.f, 0.f);
    float4 a1 = make_float4(0.f, 0.f, 0.f, 0.f);
    int j = lo;
    for (; j + 2 <= hi; j += 2) {
        unsigned e0 = (unsigned)clampi(elist[j], 0, NE - 1);
        unsigned e1 = (unsigned)clampi(elist[j + 1], 0, NE - 1);
        const unsigned short* r0 = &h[e0 * 300u + c0];
        const unsigned short* r1 = &h[e1 * 300u + c0];
        float4 v0 = ld4(r0);
        float4 w0 = ld4(r1);
        a0.x += v0.x + w0.x; a0.y += v0.y + w0.y; a0.z += v0.z + w0.z; a0.w += v0.w + w0.w;
        if (full) {
            float4 v1 = ld4(r0 + 4);
            float4 w1 = ld4(r1 + 4);
            a1.x += v1.x + w1.x; a1.y += v1.y + w1.y; a1.z += v1.z + w1.z; a1.w += v1.w + w1.w;
        }
    }
    if (j < hi) {
        unsigned e0 = (unsigned)clampi(elist[j], 0, NE - 1);
        const unsigned short* r0 = &h[e0 * 300u + c0];
        float4 v0 = ld4(r0);
        a0.x += v0.x; a0.y += v0.y; a0.z += v0.z; a0.w += v0.w;
        if (full) {
            float4 v1 = ld4(r0 + 4);
            a1.x += v1.x; a1.y += v1.y; a1.z += v1.z; a1.w += v1.w;
        }
    }
    st4(&inc[(unsigned)n * 300u + c0], a0);
    if (full) st4(&inc[(unsigned)n * 300u + c0 + 4], a1);
}

// ================= GEMM core =================
// lin/mp: 768 threads = 12 waves over a 64-row x 304-col tile (round-7 form).
// au (round 8): segsum DE-FUSED — au's stage is now FULLY DENSE (contiguous node
// rows + contiguous inc rows, ZERO gathers). Tests the hypothesis that the common
// ~116-119us of all GEMM dispatches is the 160k gathered rows inside the
// barrier-phased region (segsum does the same gather volume at 27us barrier-free).

// ---------------- lin GEMM: h[e] = relu(concat(node_in[src[e]], ea[e]) @ W + b) ----------------
template <int NID, typename TN>
__global__ __launch_bounds__(768, 6) void k_lin_mfma(
        const TN* __restrict__ node_in, const float* __restrict__ ea,
        const int* __restrict__ srcH, const int* __restrict__ dstH,
        const unsigned short* __restrict__ whi, const unsigned short* __restrict__ wlo,
        const float* __restrict__ bias, unsigned short* __restrict__ h) {
    constexpr int K = NID + 14;
    constexpr int KP = (K + 31) & ~31;                    // 160 or 320
    constexpr int NKT = KP / 32;
    constexpr int LDK = (KP + 8 < 312) ? 312 : KP + 8;
    __shared__ unsigned short As[64 * LDK];
    __shared__ int ssrc[64];
    const int tid = threadIdx.x;
    const int lane = tid & 63, wv = tid >> 6;
    const int quad = lane >> 4, cr = lane & 15;
    const int e0 = blockIdx.x * 64;
    if (tid < 64) {
        int e = e0 + tid;
        int s = (e < HALF) ? srcH[e] : dstH[e - HALF];
        ssrc[tid] = clampi(s, 0, NN - 1);
    }
    __syncthreads();
    if constexpr (NID == 300) {
        for (int idx = tid; idx < 64 * 75; idx += 768) {
            int r = idx / 75, q = idx - r * 75;
            *(ushort4*)&As[r * LDK + q * 4] =
                *(const ushort4*)&((const unsigned short*)node_in)[(unsigned)ssrc[r] * 300u + q * 4];
        }
        for (int idx = tid; idx < 64 * (KP - 300); idx += 768) {
            int r = idx / (KP - 300), k = idx - r * (KP - 300);
            int kk = 300 + k;
            float v = (kk < K) ? ea[(unsigned)(e0 + r) * 14u + (kk - 300)] : 0.f;
            As[r * LDK + kk] = f2bf_us(v);
        }
    } else {
        for (int idx = tid; idx < 64 * KP; idx += 768) {
            int r = idx / KP, k = idx - r * KP;
            float v;
            if (k < NID)    v = ld1(&node_in[(unsigned)ssrc[r] * (unsigned)NID + k]);
            else if (k < K) v = ea[(unsigned)(e0 + r) * 14u + (k - NID)];
            else            v = 0.f;
            As[r * LDK + k] = f2bf_us(v);
        }
    }
    __syncthreads();
    f32x4v acc[4][2];
    #pragma unroll
    for (int c = 0; c < 2; ++c) {
        int ct = wv + 12 * c;
        float b = 0.f;
        if (ct < 19) { int col = ct * 16 + cr; if (col < 300) b = bias[col]; }
        #pragma unroll
        for (int rt = 0; rt < 4; ++rt) { f32x4v a = {b, b, b, b}; acc[rt][c] = a; }
    }
    for (int kt = 0; kt < NKT; ++kt) {
        bf16x8v bb[2];
        #pragma unroll
        for (int c = 0; c < 2; ++c) {
            int ct = wv + 12 * c;
            if (ct < 19)
                bb[c] = *(const bf16x8v*)&wlo[((unsigned)(kt * 19 + ct) * 64u + lane) * 8u];
        }
        #pragma unroll
        for (int rt = 0; rt < 4; ++rt) {
            bf16x8v a = *(const bf16x8v*)&As[(rt * 16 + cr) * LDK + kt * 32 + quad * 8];
            #pragma unroll
            for (int c = 0; c < 2; ++c) {
                int ct = wv + 12 * c;
                if (ct >= 19) break;
                acc[rt][c] = __builtin_amdgcn_mfma_f32_16x16x32_bf16(a, bb[c], acc[rt][c], 0, 0, 0);
            }
        }
        #pragma unroll
        for (int c = 0; c < 2; ++c) {
            int ct = wv + 12 * c;
            if (ct < 19)
                bb[c] = *(const bf16x8v*)&whi[((unsigned)(kt * 19 + ct) * 64u + lane) * 8u];
        }
        #pragma unroll
        for (int rt = 0; rt < 4; ++rt) {
            bf16x8v a = *(const bf16x8v*)&As[(rt * 16 + cr) * LDK + kt * 32 + quad * 8];
            #pragma unroll
            for (int c = 0; c < 2; ++c) {
                int ct = wv + 12 * c;
                if (ct >= 19) break;
                acc[rt][c] = __builtin_amdgcn_mfma_f32_16x16x32_bf16(a, bb[c], acc[rt][c], 0, 0, 0);
            }
        }
    }
    __syncthreads();
    #pragma unroll
    for (int c = 0; c < 2; ++c) {
        int ct = wv + 12 * c;
        if (ct >= 19) break;
        int col = ct * 16 + cr;
        if (col >= 300) continue;
        #pragma unroll
        for (int rt = 0; rt < 4; ++rt)
            #pragma unroll
            for (int r = 0; r < 4; ++r)
                As[(rt * 16 + quad * 4 + r) * LDK + col] = f2bf_us(fmaxf(acc[rt][c][r], 0.f));
    }
    __syncthreads();
    for (int idx = tid; idx < 64 * 75; idx += 768) {
        int r = idx / 75, q = idx - r * 75;
        *(ushort4*)&h[(unsigned)(e0 + r) * 300u + q * 4] = *(const ushort4*)&As[r * LDK + q * 4];
    }
}

// ---------------- au GEMM (DENSE, de-fused): out[n] = (relu?)(concat(node_in[n], inc[n]) @ W + b) ----
// inc = segsum result (precomputed by k_segsum8). Stage is pure contiguous copies.
template <int NID, typename TN, bool RELU>
__global__ __launch_bounds__(512, 4) void k_au_mfma(
        const TN* __restrict__ node_in, const unsigned short* __restrict__ inc,
        const unsigned short* __restrict__ whi, const unsigned short* __restrict__ wlo,
        const float* __restrict__ bias, unsigned short* __restrict__ out_rows) {
    constexpr int K = NID + 300;
    constexpr int KP = (K + 31) & ~31;     // 448 or 608
    constexpr int NKT = KP / 32;
    constexpr int LDK = KP + 8;            // 456 / 616
    __shared__ unsigned short As[64 * LDK];
    const int tid = threadIdx.x;
    const int lane = tid & 63, wv = tid >> 6;
    const int quad = lane >> 4, cr = lane & 15;
    const int n0 = blockIdx.x * 64;
    // node part: cols [0, NID) — dense
    if constexpr (NID == 300) {
        for (int idx = tid; idx < 64 * 75; idx += 512) {
            int r = idx / 75, q = idx - r * 75;
            *(ushort4*)&As[r * LDK + q * 4] =
                *(const ushort4*)&((const unsigned short*)node_in)[(unsigned)(n0 + r) * 300u + q * 4];
        }
    } else {
        // contiguous 64-row fp32 block: flat aligned float4 copy (64*NID divisible by 4 for NID=133)
        const float* xb = (const float*)node_in + (size_t)n0 * NID;
        for (int f4 = tid; f4 < (64 * NID) / 4; f4 += 512) {
            float4 v = *(const float4*)&xb[f4 * 4];
            int f = f4 * 4;
            float vv[4] = {v.x, v.y, v.z, v.w};
            #pragma unroll
            for (int i = 0; i < 4; ++i) {
                int fi = f + i;
                int r = fi / NID, k = fi - r * NID;
                As[r * LDK + k] = f2bf_us(vv[i]);
            }
        }
    }
    // seg part: cols [NID, NID+300) — dense copy of inc rows (NO gather)
    if constexpr (NID == 300) {
        // 300 even, LDK=616: 8-byte alignment holds -> ushort4 copies
        for (int idx = tid; idx < 64 * 75; idx += 512) {
            int r = idx / 75, q = idx - r * 75;
            *(ushort4*)&As[r * LDK + 300 + q * 4] =
                *(const ushort4*)&inc[(unsigned)(n0 + r) * 300u + q * 4];
        }
    } else {
        // NID=133 odd -> LDS dest misaligned for ushort4; aligned global load + scalar LDS stores
        for (int idx = tid; idx < 64 * 75; idx += 512) {
            int r = idx / 75, q = idx - r * 75;
            ushort4 v = *(const ushort4*)&inc[(unsigned)(n0 + r) * 300u + q * 4];
            unsigned short* dst = &As[r * LDK + NID + q * 4];
            dst[0] = v.x; dst[1] = v.y; dst[2] = v.z; dst[3] = v.w;
        }
    }
    // pad: cols [NID+300, KP)
    constexpr int PAD = KP - NID - 300;
    for (int idx = tid; idx < 64 * PAD; idx += 512) {
        int r = idx / PAD, k = idx - r * PAD;
        As[r * LDK + NID + 300 + k] = 0;
    }
    __syncthreads();
    f32x4v acc[4][3];
    #pragma unroll
    for (int c = 0; c < 3; ++c) {
        int ct = wv + 8 * c;
        float b = 0.f;
        if (ct < 19) { int col = ct * 16 + cr; if (col < 300) b = bias[col]; }
        #pragma unroll
        for (int rt = 0; rt < 4; ++rt) { f32x4v a = {b, b, b, b}; acc[rt][c] = a; }
    }
    // software-pipelined K-loop (weight prefetch, register double-buffer)
    bf16x8v pbhi[2][3], pblo[2][3];
    #pragma unroll
    for (int c = 0; c < 3; ++c) {
        int ct = wv + 8 * c;
        if (ct < 19) {
            unsigned base = ((unsigned)ct * 64u + lane) * 8u;
            pbhi[0][c] = *(const bf16x8v*)&whi[base];
            pblo[0][c] = *(const bf16x8v*)&wlo[base];
        }
    }
    #pragma unroll
    for (int kt = 0; kt < NKT; ++kt) {
        const int cur = kt & 1, nxt = cur ^ 1;
        if (kt + 1 < NKT) {
            #pragma unroll
            for (int c = 0; c < 3; ++c) {
                int ct = wv + 8 * c;
                if (ct < 19) {
                    unsigned base = ((unsigned)((kt + 1) * 19 + ct) * 64u + lane) * 8u;
                    pbhi[nxt][c] = *(const bf16x8v*)&whi[base];
                    pblo[nxt][c] = *(const bf16x8v*)&wlo[base];
                }
            }
        }
        #pragma unroll
        for (int rt = 0; rt < 4; ++rt) {
            bf16x8v a = *(const bf16x8v*)&As[(rt * 16 + cr) * LDK + kt * 32 + quad * 8];
            #pragma unroll
            for (int c = 0; c < 3; ++c) {
                int ct = wv + 8 * c;
                if (ct >= 19) break;
                acc[rt][c] = __builtin_amdgcn_mfma_f32_16x16x32_bf16(a, pblo[cur][c], acc[rt][c], 0, 0, 0);
                acc[rt][c] = __builtin_amdgcn_mfma_f32_16x16x32_bf16(a, pbhi[cur][c], acc[rt][c], 0, 0, 0);
            }
        }
    }
    __syncthreads();
    #pragma unroll
    for (int c = 0; c < 3; ++c) {
        int ct = wv + 8 * c;
        if (ct >= 19) break;
        int col = ct * 16 + cr;
        if (col >= 300) continue;
        #pragma unroll
        for (int rt = 0; rt < 4; ++rt)
            #pragma unroll
            for (int r = 0; r < 4; ++r) {
                float v = acc[rt][c][r];
                As[(rt * 16 + quad * 4 + r) * LDK + col] = f2bf_us(RELU ? fmaxf(v, 0.f) : v);
            }
    }
    __syncthreads();
    for (int idx = tid; idx < 64 * 75; idx += 512) {
        int r = idx / 75, q = idx - r * 75;
        *(ushort4*)&out_rows[(unsigned)(n0 + r) * 300u + q * 4] = *(const ushort4*)&As[r * LDK + q * 4];
    }
}

// ---------------- mp GEMM: h[e] = relu(h[e] + (inc[src[e]] - h[rev(e)]) @ W + b) ----------------
// 64 rows = 32 pairs / block. Operand (inc[src]-h[pair]) staged directly from global
// in one pass; +h[e]+bias applied in the EPILOGUE from global. 12 waves.
__global__ __launch_bounds__(768, 6) void k_mp_mfma(
        unsigned short* __restrict__ h, const unsigned short* __restrict__ inc,
        const int* __restrict__ srcH, const int* __restrict__ dstH,
        const unsigned short* __restrict__ whi, const unsigned short* __restrict__ wlo,
        const float* __restrict__ bias) {
    constexpr int LDK = 328;
    __shared__ unsigned short Hs[64 * LDK];
    __shared__ int ssrc[64];
    const int tid = threadIdx.x;
    const int lane = tid & 63, wv = tid >> 6;
    const int quad = lane >> 4, cr = lane & 15;
    const int p0 = blockIdx.x * 32;
    if (tid < 64) {
        int r = tid;
        int e = (r < 32) ? (p0 + r) : (p0 + r - 32 + HALF);
        int s = (e < HALF) ? srcH[e] : dstH[e - HALF];
        ssrc[r] = clampi(s, 0, NN - 1);
    }
    __syncthreads();
    // single-pass operand staging: Hs[r] = inc[src[e_r]] - h[pair(e_r)], zero-pad to KP=320
    for (int idx = tid; idx < 64 * 80; idx += 768) {
        int r = idx / 80, q = idx - r * 80;
        int col = q * 4;
        if (col < 300) {
            unsigned ep = (r < 32) ? (unsigned)(p0 + r + HALF) : (unsigned)(p0 + r - 32);
            float4 hp = ld4(&h[ep * 300u + col]);
            float4 iv = ld4(&inc[(unsigned)ssrc[r] * 300u + col]);
            st4(&Hs[r * LDK + col],
                make_float4(iv.x - hp.x, iv.y - hp.y, iv.z - hp.z, iv.w - hp.w));
        } else {
            *(ushort4*)&Hs[r * LDK + col] = make_ushort4(0, 0, 0, 0);
        }
    }
    __syncthreads();
    f32x4v acc[4][2];
    #pragma unroll
    for (int c = 0; c < 2; ++c)
        #pragma unroll
        for (int rt = 0; rt < 4; ++rt) {
            f32x4v a = {0.f, 0.f, 0.f, 0.f};
            acc[rt][c] = a;
        }
    for (int kt = 0; kt < 10; ++kt) {
        bf16x8v bb[2];
        #pragma unroll
        for (int c = 0; c < 2; ++c) {
            int ct = wv + 12 * c;
            if (ct < 19)
                bb[c] = *(const bf16x8v*)&wlo[((unsigned)(kt * 19 + ct) * 64u + lane) * 8u];
        }
        #pragma unroll
        for (int rt = 0; rt < 4; ++rt) {
            bf16x8v a = *(const bf16x8v*)&Hs[(rt * 16 + cr) * LDK + kt * 32 + quad * 8];
            #pragma unroll
            for (int c = 0; c < 2; ++c) {
                int ct = wv + 12 * c;
                if (ct >= 19) break;
                acc[rt][c] = __builtin_amdgcn_mfma_f32_16x16x32_bf16(a, bb[c], acc[rt][c], 0, 0, 0);
            }
        }
        #pragma unroll
        for (int c = 0; c < 2; ++c) {
            int ct = wv + 12 * c;
            if (ct < 19)
                bb[c] = *(const bf16x8v*)&whi[((unsigned)(kt * 19 + ct) * 64u + lane) * 8u];
        }
        #pragma unroll
        for (int rt = 0; rt < 4; ++rt) {
            bf16x8v a = *(const bf16x8v*)&Hs[(rt * 16 + cr) * LDK + kt * 32 + quad * 8];
            #pragma unroll
            for (int c = 0; c < 2; ++c) {
                int ct = wv + 12 * c;
                if (ct >= 19) break;
                acc[rt][c] = __builtin_amdgcn_mfma_f32_16x16x32_bf16(a, bb[c], acc[rt][c], 0, 0, 0);
            }
        }
    }
    __syncthreads();   // all GEMM reads of Hs done before epilogue overwrites
    #pragma unroll
    for (int c = 0; c < 2; ++c) {
        int ct = wv + 12 * c;
        if (ct >= 19) break;
        int col = ct * 16 + cr;
        if (col >= 300) continue;
        float bv = bias[col];
        #pragma unroll
        for (int rt = 0; rt < 4; ++rt)
            #pragma unroll
            for (int r = 0; r < 4; ++r) {
                int row = rt * 16 + quad * 4 + r;
                unsigned e = (row < 32) ? (unsigned)(p0 + row) : (unsigned)(p0 + row - 32 + HALF);
                float hv = bf2f_us(h[e * 300u + col]);   // L1/L2-hot own row
                Hs[row * LDK + col] = f2bf_us(fmaxf(acc[rt][c][r] + bv + hv, 0.f));
            }
    }
    __syncthreads();
    for (int idx = tid; idx < 64 * 75; idx += 768) {
        int r = idx / 75, q = idx - r * 75;
        unsigned e = (r < 32) ? (unsigned)(p0 + r) : (unsigned)(p0 + r - 32 + HALF);
        *(ushort4*)&h[e * 300u + q * 4] = *(const ushort4*)&Hs[r * LDK + q * 4];
    }
}

// ---------------- pooling (bf16 rows) + reparam ----------------
__global__ __launch_bounds__(320) void k_pool(const unsigned short* __restrict__ rows,
                                              const float* __restrict__ wat,
                                              const int* __restrict__ gs, float* __restrict__ outg) {
    int g = blockIdx.x, c = threadIdx.x;
    if (c >= 300) return;
    int lo = clampi(gs[g], 0, NN), hi = clampi(gs[g + 1], 0, NN);
    float acc = 0.f;
    for (int n = lo; n < hi; ++n)
        acc += bf2f_us(rows[(unsigned)n * 300u + c]) * wat[n];
    float cn = fmaxf((float)(hi - lo), 1.f);
    outg[g * 300 + c] = acc / cn;
}
__global__ __launch_bounds__(320) void k_final(const float* __restrict__ mu_g, const float* __restrict__ lv_g,
                                               const float* __restrict__ eps, float* __restrict__ out) {
    int g = blockIdx.x, c = threadIdx.x;
    if (c >= 300) return;
    out[g * 300 + c] = mu_g[g * 300 + c] + expf(0.5f * lv_g[g * 300 + c]) * eps[g * 300 + c];
}

extern "C" void kernel_launch(void* const* d_in, const int* in_sizes, int n_in,
                              void* d_out, int out_size, void* d_ws, size_t ws_size,
                              hipStream_t stream) {
    float* outp = (float*)d_out;

    const size_t NEED = 199500000ull;   // carve ~199.43 MB; ws proven >= 200,000,000
    if (ws_size < NEED) {
        k_zerof<<<(out_size + 255) / 256, 256, 0, stream>>>(outp, out_size);
        return;
    }

    const float* x   = (const float*)d_in[0];
    const float* ea  = (const float*)d_in[1];
    const float* wat = (const float*)d_in[2];
    const float* eps = (const float*)d_in[3];
    const int* srcH  = (const int*)d_in[4];
    const int* dstH  = (const int*)d_in[5];
    const int* batch = (const int*)d_in[6];
    const float* w_t_lin  = (const float*)d_in[7];
    const float* b_t_lin  = (const float*)d_in[8];
    const float* w_t_mp   = (const float*)d_in[9];
    const float* b_t_mp   = (const float*)d_in[10];
    const float* w_t_au   = (const float*)d_in[11];
    const float* b_t_au   = (const float*)d_in[12];
    const float* w_mu_lin = (const float*)d_in[13];
    const float* b_mu_lin = (const float*)d_in[14];
    const float* w_mu_mp  = (const float*)d_in[15];
    const float* b_mu_mp  = (const float*)d_in[16];
    const float* w_mu_au  = (const float*)d_in[17];
    const float* b_mu_au  = (const float*)d_in[18];
    const float* w_lv_lin = (const float*)d_in[19];
    const float* b_lv_lin = (const float*)d_in[20];
    const float* w_lv_mp  = (const float*)d_in[21];
    const float* b_lv_mp  = (const float*)d_in[22];
    const float* w_lv_au  = (const float*)d_in[23];
    const float* b_lv_au  = (const float*)d_in[24];

    char* p = (char*)d_ws;
    auto alloc = [&](size_t nbytes) { char* q = p; p += (nbytes + 255) & ~(size_t)255; return q; };
    unsigned short* h   = (unsigned short*)alloc((size_t)NE * 300 * 2);   // 96 MB
    unsigned short* inc = (unsigned short*)alloc((size_t)NN * 300 * 2);   // 48 MB (segsum result)
    unsigned short* sh  = (unsigned short*)alloc((size_t)NN * 300 * 2);   // 48 MB
    const size_t MPU = (size_t)3 * 10 * 19 * 512;   // mp tables (ushorts)
    unsigned short* wh_mp = (unsigned short*)alloc(MPU * 2);
    unsigned short* wl_mp = (unsigned short*)alloc(MPU * 2);
    const size_t LAU = (size_t)29 * 19 * 512;       // lin+au tables
    unsigned short* wh_la = (unsigned short*)alloc(LAU * 2);
    unsigned short* wl_la = (unsigned short*)alloc(LAU * 2);
    float* mu_g = (float*)alloc((size_t)NG * 300 * 4);
    float* lv_g = (float*)alloc((size_t)NG * 300 * 4);
    int* deg    = (int*)alloc(NN * 4);               // reused as cursor (alias-safe)
    int* startA = (int*)alloc((NN + 1) * 4);
    int* elist  = (int*)alloc(NE * 4);
    int* degg   = (int*)alloc(NG * 4);
    int* gs     = (int*)alloc((NG + 1) * 4);
    int* part   = (int*)alloc(SCB * 4);

    // ---- CSR (incoming by dst), multi-block scan; cursor aliases deg ----
    k_zeroi<<<(NN + 255) / 256, 256, 0, stream>>>(deg, NN);
    k_hist<<<(NE + 255) / 256, 256, 0, stream>>>(srcH, dstH, deg);
    k_scan_part<<<SCB, 256, 0, stream>>>(deg, part, NN);
    k_scan_offsets<<<1, 256, 0, stream>>>(part);
    k_scan_apply<<<SCB, 256, 0, stream>>>(deg, part, startA, deg, NN);
    k_fill<<<(NE + 255) / 256, 256, 0, stream>>>(srcH, dstH, deg, elist);
    // ---- graph-CSR over sorted batch ----
    k_zeroi<<<(NG + 255) / 256, 256, 0, stream>>>(degg, NG);
    k_histg<<<(NN + 255) / 256, 256, 0, stream>>>(batch, degg);
    k_scan_part<<<SCB, 256, 0, stream>>>(degg, part, NG);
    k_scan_offsets<<<1, 256, 0, stream>>>(part);
    k_scan_apply<<<SCB, 256, 0, stream>>>(degg, part, gs, (int*)nullptr, NG);

    const int SSG = (NN * 38 + 255) / 256;
    const size_t MP_L = (size_t)10 * 19 * 512;      // ushorts per mp layer
    auto wsplit_conv = [&](const float* Wmp, const float* Wlin, int Klin, int nktlin,
                           const float* Wau, int Kau, int nktau) {
        int total = 570 + nktlin * 19 + nktau * 19;
        k_wsplit_conv<<<(total * 64 + 255) / 256, 256, 0, stream>>>(
            Wmp, Wlin, Klin, nktlin, Wau, Kau, nktau, wh_mp, wl_mp, wh_la, wl_la);
    };

    // ================= conv t =================
    wsplit_conv(w_t_mp, w_t_lin, 147, 5, w_t_au, 433, 14);
    const size_t AU_T = (size_t)5 * 19 * 512;
    k_lin_mfma<133, float><<<NE / 64, 768, 0, stream>>>(x, ea, srcH, dstH, wh_la, wl_la, b_t_lin, h);
    for (int i = 0; i < 3; ++i) {
        k_segsum8<<<SSG, 256, 0, stream>>>(h, elist, startA, inc);
        k_mp_mfma<<<HALF / 32, 768, 0, stream>>>(h, inc, srcH, dstH,
                                                 wh_mp + i * MP_L, wl_mp + i * MP_L, b_t_mp + i * 300);
    }
    // de-fused au: segsum first (streaming, roofline), then fully dense au GEMM
    k_segsum8<<<SSG, 256, 0, stream>>>(h, elist, startA, inc);
    k_au_mfma<133, float, true><<<NN / 64, 512, 0, stream>>>(x, inc,
                                                             wh_la + AU_T, wl_la + AU_T, b_t_au, sh);

    // ================= conv mu =================
    wsplit_conv(w_mu_mp, w_mu_lin, 314, 10, w_mu_au, 600, 19);
    const size_t AU_MU = (size_t)10 * 19 * 512;
    k_lin_mfma<300, unsigned short><<<NE / 64, 768, 0, stream>>>(sh, ea, srcH, dstH, wh_la, wl_la, b_mu_lin, h);
    for (int i = 0; i < 3; ++i) {
        k_segsum8<<<SSG, 256, 0, stream>>>(h, elist, startA, inc);
        k_mp_mfma<<<HALF / 32, 768, 0, stream>>>(h, inc, srcH, dstH,
                                                 wh_mp + i * MP_L, wl_mp + i * MP_L, b_mu_mp + i * 300);
    }
    // de-fused au: after this segsum, h is DEAD (au reads only sh + inc) -> au output
    // lives in the h buffer's first 48 MB; pool consumes it before lv's lin rewrites h.
    k_segsum8<<<SSG, 256, 0, stream>>>(h, elist, startA, inc);
    {
        unsigned short* rows = h;
        k_au_mfma<300, unsigned short, false><<<NN / 64, 512, 0, stream>>>(sh, inc,
                                                                           wh_la + AU_MU, wl_la + AU_MU, b_mu_au, rows);
        k_pool<<<NG, 320, 0, stream>>>(rows, wat, gs, mu_g);
    }

    // ================= conv lv =================
    wsplit_conv(w_lv_mp, w_lv_lin, 314, 10, w_lv_au, 600, 19);
    k_lin_mfma<300, unsigned short><<<NE / 64, 768, 0, stream>>>(sh, ea, srcH, dstH, wh_la, wl_la, b_lv_lin, h);
    for (int i = 0; i < 3; ++i) {
        k_segsum8<<<SSG, 256, 0, stream>>>(h, elist, startA, inc);
        k_mp_mfma<<<HALF / 32, 768, 0, stream>>>(h, inc, srcH, dstH,
                                                 wh_mp + i * MP_L, wl_mp + i * MP_L, b_lv_mp + i * 300);
    }
    k_segsum8<<<SSG, 256, 0, stream>>>(h, elist, startA, inc);
    {
        unsigned short* rows = h;
        k_au_mfma<300, unsigned short, false><<<NN / 64, 512, 0, stream>>>(sh, inc,
                                                                           wh_la + AU_MU, wl_la + AU_MU, b_lv_au, rows);
        k_pool<<<NG, 320, 0, stream>>>(rows, wat, gs, lv_g);
    }

    // ---- reparam ----
    k_final<<<NG, 320, 0, stream>>>(mu_g, lv_g, eps, outp);
}

// Round 9
// 1934.823 us; speedup vs baseline: 1.0634x; 1.0424x over previous
//
#include <hip/hip_runtime.h>
#include <hip/hip_bf16.h>

#define NN 80000       // nodes
#define NE 160000      // edges (both directions)
#define HALF 80000
#define HID 300
#define NG 1600
#define SCB 256        // scan blocks

typedef __attribute__((ext_vector_type(8))) short bf16x8v;
typedef __attribute__((ext_vector_type(4))) float f32x4v;

// ---------------- helpers ----------------
__device__ __forceinline__ float bf2f_us(unsigned short u) {
    return __uint_as_float(((unsigned int)u) << 16);
}
// native RNE convert: lowers to v_cvt_pk_bf16_f32 on gfx950
__device__ __forceinline__ unsigned short f2bf_us(float f) {
    union { __bf16 b; unsigned short u; } cv;
    cv.b = (__bf16)f;
    return cv.u;
}
__device__ __forceinline__ float ld1(const float* p) { return *p; }
__device__ __forceinline__ float ld1(const unsigned short* p) { return bf2f_us(*p); }
__device__ __forceinline__ float4 ld4(const float* p) { return *(const float4*)p; }
__device__ __forceinline__ float4 ld4(const unsigned short* p) {
    ushort4 u = *(const ushort4*)p;
    return make_float4(bf2f_us(u.x), bf2f_us(u.y), bf2f_us(u.z), bf2f_us(u.w));
}
__device__ __forceinline__ void st4(float* p, float4 v) { *(float4*)p = v; }
__device__ __forceinline__ void st4(unsigned short* p, float4 v) {
    ushort4 u; u.x = f2bf_us(v.x); u.y = f2bf_us(v.y); u.z = f2bf_us(v.z); u.w = f2bf_us(v.w);
    *(ushort4*)p = u;
}
__device__ __forceinline__ int clampi(int v, int lo, int hi) {
    return v < lo ? lo : (v > hi ? hi : v);
}

// ---------------- zero-fill ----------------
__global__ void k_zerof(float* __restrict__ p, int n) {
    int i = blockIdx.x * 256 + threadIdx.x; if (i < n) p[i] = 0.f;
}
__global__ void k_zeroi(int* __restrict__ p, int n) {
    int i = blockIdx.x * 256 + threadIdx.x; if (i < n) p[i] = 0;
}

// ---------------- merged per-conv W split: mp(3 layers) + lin + au in ONE dispatch ----------------
// fragment order per tile t: lane holds B[k=kt*32+quad*8+j][n=ct*16+(lane&15)], j=0..7
__global__ void k_wsplit_conv(const float* __restrict__ Wmp,
                              const float* __restrict__ Wlin, int Klin, int nktlin,
                              const float* __restrict__ Wau, int Kau, int nktau,
                              unsigned short* __restrict__ wh_mp, unsigned short* __restrict__ wl_mp,
                              unsigned short* __restrict__ wh_la, unsigned short* __restrict__ wl_la) {
    const int MP_L = 10 * 19 * 512;   // ushorts per mp layer
    int idx = blockIdx.x * 256 + threadIdx.x;
    int total = 570 + nktlin * 19 + nktau * 19;
    int t = idx >> 6;
    if (t >= total) return;
    int lane = idx & 63;
    const float* W; int Krows, ltile;
    unsigned short *whi, *wlo;
    if (t < 570) {                       // mp: 3 layers x 190 tiles
        int l = t / 190, rem = t - l * 190;
        W = Wmp + l * 90000; Krows = 300; ltile = rem;
        whi = wh_mp + l * MP_L; wlo = wl_mp + l * MP_L;
    } else if (t < 570 + nktlin * 19) {  // lin at la offset 0
        ltile = t - 570; W = Wlin; Krows = Klin;
        whi = wh_la; wlo = wl_la;
    } else {                             // au after lin tiles
        ltile = t - 570 - nktlin * 19; W = Wau; Krows = Kau;
        size_t off = (size_t)nktlin * 19 * 512;
        whi = wh_la + off; wlo = wl_la + off;
    }
    int kt = ltile / 19, ct = ltile - kt * 19;
    int quad = lane >> 4, cr = lane & 15;
    unsigned obase = ((unsigned)ltile * 64u + lane) * 8u;
    for (int j = 0; j < 8; ++j) {
        int k = kt * 32 + quad * 8 + j;
        int n = ct * 16 + cr;
        float v = (k < Krows && n < 300) ? W[(unsigned)k * 300u + n] : 0.f;
        unsigned short hu = f2bf_us(v);
        unsigned short lu = f2bf_us(v - bf2f_us(hu));
        whi[obase + j] = hu;
        wlo[obase + j] = lu;
    }
}

// ---------------- CSR build ----------------
__global__ void k_hist(const int* __restrict__ srcH, const int* __restrict__ dstH, int* __restrict__ deg) {
    int e = blockIdx.x * 256 + threadIdx.x;
    if (e >= NE) return;
    int d = (e < HALF) ? dstH[e] : srcH[e - HALF];
    d = clampi(d, 0, NN - 1);
    atomicAdd(&deg[d], 1);
}
__global__ void k_histg(const int* __restrict__ batch, int* __restrict__ degg) {
    int n = blockIdx.x * 256 + threadIdx.x;
    if (n >= NN) return;
    atomicAdd(&degg[clampi(batch[n], 0, NG - 1)], 1);
}

// ---------------- 3-phase multi-block exclusive scan ----------------
__global__ __launch_bounds__(256) void k_scan_part(const int* __restrict__ deg, int* __restrict__ part, int n) {
    __shared__ int red[256];
    int b = blockIdx.x, t = threadIdx.x;
    int chunk = (n + SCB - 1) / SCB;
    int lo = b * chunk, hi = lo + chunk; if (hi > n) hi = n;
    int s = 0;
    for (int i = lo + t; i < hi; i += 256) s += deg[i];
    red[t] = s;
    __syncthreads();
    for (int off = 128; off > 0; off >>= 1) {
        if (t < off) red[t] += red[t + off];
        __syncthreads();
    }
    if (t == 0) part[b] = red[0];
}
__global__ __launch_bounds__(256) void k_scan_offsets(int* __restrict__ part) {
    __shared__ int sh[256];
    int t = threadIdx.x;
    sh[t] = part[t];
    __syncthreads();
    for (int off = 1; off < 256; off <<= 1) {
        int v = (t >= off) ? sh[t - off] : 0;
        __syncthreads();
        sh[t] += v;
        __syncthreads();
    }
    part[t] = (t == 0) ? 0 : sh[t - 1];
}
__global__ __launch_bounds__(256) void k_scan_apply(const int* __restrict__ deg, const int* __restrict__ part,
                                                    int* __restrict__ start, int* cursor, int n) {
    __shared__ int sh[256];
    int b = blockIdx.x, t = threadIdx.x;
    int chunk = (n + SCB - 1) / SCB;
    int lo = b * chunk, hi = lo + chunk; if (hi > n) hi = n;
    int sub = (chunk + 255) / 256;
    int slo = lo + t * sub, shi = slo + sub;
    if (slo > hi) slo = hi;
    if (shi > hi) shi = hi;
    int s = 0;
    for (int i = slo; i < shi; ++i) s += deg[i];
    sh[t] = s;
    __syncthreads();
    for (int off = 1; off < 256; off <<= 1) {
        int v = (t >= off) ? sh[t - off] : 0;
        __syncthreads();
        sh[t] += v;
        __syncthreads();
    }
    int run = part[b] + sh[t] - s;
    for (int i = slo; i < shi; ++i) {
        int d = deg[i];              // read before aliased cursor write
        start[i] = run;
        if (cursor) cursor[i] = run;
        run += d;
    }
    if (b == SCB - 1 && t == 255) start[n] = run;
}

__global__ void k_fill(const int* __restrict__ srcH, const int* __restrict__ dstH,
                       int* __restrict__ cursor, int* __restrict__ elist) {
    int e = blockIdx.x * 256 + threadIdx.x;
    if (e >= NE) return;
    int d = (e < HALF) ? dstH[e] : srcH[e - HALF];
    d = clampi(d, 0, NN - 1);
    int pos = atomicAdd(&cursor[d], 1);
    if (pos >= 0 && pos < NE) elist[pos] = e;
}

// ---------------- segment sum: thread per (node, 8-col group) ----------------
// Measured at ~5.4-6 TB/s (roofline for this gather). Feeds mp and the de-fused au.
__global__ __launch_bounds__(256) void k_segsum8(const unsigned short* __restrict__ h,
                                                 const int* __restrict__ elist,
                                                 const int* __restrict__ start,
                                                 unsigned short* __restrict__ inc) {
    int t = blockIdx.x * 256 + threadIdx.x;
    if (t >= NN * 38) return;
    int n = t / 38, q = t - n * 38;
    int c0 = q * 8;
    bool full = (c0 + 8 <= 300);
    int lo = clampi(start[n], 0, NE), hi = clampi(start[n + 1], 0, NE);
    float4 a0 = make_float4(0.f, 0.f, 0.f, 0.f);
    float4 a1 = make_float4(0.f, 0.f, 0.f, 0.f);
    int j = lo;
    for (; j + 2 <= hi; j += 2) {
        unsigned e0 = (unsigned)clampi(elist[j], 0, NE - 1);
        unsigned e1 = (unsigned)clampi(elist[j + 1], 0, NE - 1);
        const unsigned short* r0 = &h[e0 * 300u + c0];
        const unsigned short* r1 = &h[e1 * 300u + c0];
        float4 v0 = ld4(r0);
        float4 w0 = ld4(r1);
        a0.x += v0.x + w0.x; a0.y += v0.y + w0.y; a0.z += v0.z + w0.z; a0.w += v0.w + w0.w;
        if (full) {
            float4 v1 = ld4(r0 + 4);
            float4 w1 = ld4(r1 + 4);
            a1.x += v1.x + w1.x; a1.y += v1.y + w1.y; a1.z += v1.z + w1.z; a1.w += v1.w + w1.w;
        }
    }
    if (j < hi) {
        unsigned e0 = (unsigned)clampi(elist[j], 0, NE - 1);
        const unsigned short* r0 = &h[e0 * 300u + c0];
        float4 v0 = ld4(r0);
        a0.x += v0.x; a0.y += v0.y; a0.z += v0.z; a0.w += v0.w;
        if (full) {
            float4 v1 = ld4(r0 + 4);
            a1.x += v1.x; a1.y += v1.y; a1.z += v1.z; a1.w += v1.w;
        }
    }
    st4(&inc[(unsigned)n * 300u + c0], a0);
    if (full) st4(&inc[(unsigned)n * 300u + c0 + 4], a1);
}

// ================= GEMM core =================
// lin/mp: 768 threads = 12 waves over a 64-row x 304-col tile.
// au: segsum de-fused, fully dense stage (round-8 proven, ~80us).
// mp (round 9): the stage already reads ALL 64 own-h rows (as the pair operand) —
// tee the raw bf16 into a second LDS tile Hs2[r^32] so the epilogue's +h[e] reads
// LDS instead of 94 MB of scalar 2B col-strided global loads (the r1 FETCH anomaly).

// ---------------- lin GEMM: h[e] = relu(concat(node_in[src[e]], ea[e]) @ W + b) ----------------
template <int NID, typename TN>
__global__ __launch_bounds__(768, 6) void k_lin_mfma(
        const TN* __restrict__ node_in, const float* __restrict__ ea,
        const int* __restrict__ srcH, const int* __restrict__ dstH,
        const unsigned short* __restrict__ whi, const unsigned short* __restrict__ wlo,
        const float* __restrict__ bias, unsigned short* __restrict__ h) {
    constexpr int K = NID + 14;
    constexpr int KP = (K + 31) & ~31;                    // 160 or 320
    constexpr int NKT = KP / 32;
    constexpr int LDK = (KP + 8 < 312) ? 312 : KP + 8;
    __shared__ unsigned short As[64 * LDK];
    __shared__ int ssrc[64];
    const int tid = threadIdx.x;
    const int lane = tid & 63, wv = tid >> 6;
    const int quad = lane >> 4, cr = lane & 15;
    const int e0 = blockIdx.x * 64;
    if (tid < 64) {
        int e = e0 + tid;
        int s = (e < HALF) ? srcH[e] : dstH[e - HALF];
        ssrc[tid] = clampi(s, 0, NN - 1);
    }
    __syncthreads();
    if constexpr (NID == 300) {
        for (int idx = tid; idx < 64 * 75; idx += 768) {
            int r = idx / 75, q = idx - r * 75;
            *(ushort4*)&As[r * LDK + q * 4] =
                *(const ushort4*)&((const unsigned short*)node_in)[(unsigned)ssrc[r] * 300u + q * 4];
        }
        for (int idx = tid; idx < 64 * (KP - 300); idx += 768) {
            int r = idx / (KP - 300), k = idx - r * (KP - 300);
            int kk = 300 + k;
            float v = (kk < K) ? ea[(unsigned)(e0 + r) * 14u + (kk - 300)] : 0.f;
            As[r * LDK + kk] = f2bf_us(v);
        }
    } else {
        for (int idx = tid; idx < 64 * KP; idx += 768) {
            int r = idx / KP, k = idx - r * KP;
            float v;
            if (k < NID)    v = ld1(&node_in[(unsigned)ssrc[r] * (unsigned)NID + k]);
            else if (k < K) v = ea[(unsigned)(e0 + r) * 14u + (k - NID)];
            else            v = 0.f;
            As[r * LDK + k] = f2bf_us(v);
        }
    }
    __syncthreads();
    f32x4v acc[4][2];
    #pragma unroll
    for (int c = 0; c < 2; ++c) {
        int ct = wv + 12 * c;
        float b = 0.f;
        if (ct < 19) { int col = ct * 16 + cr; if (col < 300) b = bias[col]; }
        #pragma unroll
        for (int rt = 0; rt < 4; ++rt) { f32x4v a = {b, b, b, b}; acc[rt][c] = a; }
    }
    for (int kt = 0; kt < NKT; ++kt) {
        bf16x8v bb[2];
        #pragma unroll
        for (int c = 0; c < 2; ++c) {
            int ct = wv + 12 * c;
            if (ct < 19)
                bb[c] = *(const bf16x8v*)&wlo[((unsigned)(kt * 19 + ct) * 64u + lane) * 8u];
        }
        #pragma unroll
        for (int rt = 0; rt < 4; ++rt) {
            bf16x8v a = *(const bf16x8v*)&As[(rt * 16 + cr) * LDK + kt * 32 + quad * 8];
            #pragma unroll
            for (int c = 0; c < 2; ++c) {
                int ct = wv + 12 * c;
                if (ct >= 19) break;
                acc[rt][c] = __builtin_amdgcn_mfma_f32_16x16x32_bf16(a, bb[c], acc[rt][c], 0, 0, 0);
            }
        }
        #pragma unroll
        for (int c = 0; c < 2; ++c) {
            int ct = wv + 12 * c;
            if (ct < 19)
                bb[c] = *(const bf16x8v*)&whi[((unsigned)(kt * 19 + ct) * 64u + lane) * 8u];
        }
        #pragma unroll
        for (int rt = 0; rt < 4; ++rt) {
            bf16x8v a = *(const bf16x8v*)&As[(rt * 16 + cr) * LDK + kt * 32 + quad * 8];
            #pragma unroll
            for (int c = 0; c < 2; ++c) {
                int ct = wv + 12 * c;
                if (ct >= 19) break;
                acc[rt][c] = __builtin_amdgcn_mfma_f32_16x16x32_bf16(a, bb[c], acc[rt][c], 0, 0, 0);
            }
        }
    }
    __syncthreads();
    #pragma unroll
    for (int c = 0; c < 2; ++c) {
        int ct = wv + 12 * c;
        if (ct >= 19) break;
        int col = ct * 16 + cr;
        if (col >= 300) continue;
        #pragma unroll
        for (int rt = 0; rt < 4; ++rt)
            #pragma unroll
            for (int r = 0; r < 4; ++r)
                As[(rt * 16 + quad * 4 + r) * LDK + col] = f2bf_us(fmaxf(acc[rt][c][r], 0.f));
    }
    __syncthreads();
    for (int idx = tid; idx < 64 * 75; idx += 768) {
        int r = idx / 75, q = idx - r * 75;
        *(ushort4*)&h[(unsigned)(e0 + r) * 300u + q * 4] = *(const ushort4*)&As[r * LDK + q * 4];
    }
}

// ---------------- au GEMM (DENSE, de-fused): out[n] = (relu?)(concat(node_in[n], inc[n]) @ W + b) ----
// inc = segsum result (precomputed by k_segsum8). Stage is pure contiguous copies.
template <int NID, typename TN, bool RELU>
__global__ __launch_bounds__(512, 4) void k_au_mfma(
        const TN* __restrict__ node_in, const unsigned short* __restrict__ inc,
        const unsigned short* __restrict__ whi, const unsigned short* __restrict__ wlo,
        const float* __restrict__ bias, unsigned short* __restrict__ out_rows) {
    constexpr int K = NID + 300;
    constexpr int KP = (K + 31) & ~31;     // 448 or 608
    constexpr int NKT = KP / 32;
    constexpr int LDK = KP + 8;            // 456 / 616
    __shared__ unsigned short As[64 * LDK];
    const int tid = threadIdx.x;
    const int lane = tid & 63, wv = tid >> 6;
    const int quad = lane >> 4, cr = lane & 15;
    const int n0 = blockIdx.x * 64;
    // node part: cols [0, NID) — dense
    if constexpr (NID == 300) {
        for (int idx = tid; idx < 64 * 75; idx += 512) {
            int r = idx / 75, q = idx - r * 75;
            *(ushort4*)&As[r * LDK + q * 4] =
                *(const ushort4*)&((const unsigned short*)node_in)[(unsigned)(n0 + r) * 300u + q * 4];
        }
    } else {
        // contiguous 64-row fp32 block: flat aligned float4 copy (64*NID divisible by 4 for NID=133)
        const float* xb = (const float*)node_in + (size_t)n0 * NID;
        for (int f4 = tid; f4 < (64 * NID) / 4; f4 += 512) {
            float4 v = *(const float4*)&xb[f4 * 4];
            int f = f4 * 4;
            float vv[4] = {v.x, v.y, v.z, v.w};
            #pragma unroll
            for (int i = 0; i < 4; ++i) {
                int fi = f + i;
                int r = fi / NID, k = fi - r * NID;
                As[r * LDK + k] = f2bf_us(vv[i]);
            }
        }
    }
    // seg part: cols [NID, NID+300) — dense copy of inc rows (NO gather)
    if constexpr (NID == 300) {
        for (int idx = tid; idx < 64 * 75; idx += 512) {
            int r = idx / 75, q = idx - r * 75;
            *(ushort4*)&As[r * LDK + 300 + q * 4] =
                *(const ushort4*)&inc[(unsigned)(n0 + r) * 300u + q * 4];
        }
    } else {
        // NID=133 odd -> LDS dest misaligned for ushort4; aligned global load + scalar LDS stores
        for (int idx = tid; idx < 64 * 75; idx += 512) {
            int r = idx / 75, q = idx - r * 75;
            ushort4 v = *(const ushort4*)&inc[(unsigned)(n0 + r) * 300u + q * 4];
            unsigned short* dst = &As[r * LDK + NID + q * 4];
            dst[0] = v.x; dst[1] = v.y; dst[2] = v.z; dst[3] = v.w;
        }
    }
    // pad: cols [NID+300, KP)
    constexpr int PAD = KP - NID - 300;
    for (int idx = tid; idx < 64 * PAD; idx += 512) {
        int r = idx / PAD, k = idx - r * PAD;
        As[r * LDK + NID + 300 + k] = 0;
    }
    __syncthreads();
    f32x4v acc[4][3];
    #pragma unroll
    for (int c = 0; c < 3; ++c) {
        int ct = wv + 8 * c;
        float b = 0.f;
        if (ct < 19) { int col = ct * 16 + cr; if (col < 300) b = bias[col]; }
        #pragma unroll
        for (int rt = 0; rt < 4; ++rt) { f32x4v a = {b, b, b, b}; acc[rt][c] = a; }
    }
    // software-pipelined K-loop (weight prefetch, register double-buffer)
    bf16x8v pbhi[2][3], pblo[2][3];
    #pragma unroll
    for (int c = 0; c < 3; ++c) {
        int ct = wv + 8 * c;
        if (ct < 19) {
            unsigned base = ((unsigned)ct * 64u + lane) * 8u;
            pbhi[0][c] = *(const bf16x8v*)&whi[base];
            pblo[0][c] = *(const bf16x8v*)&wlo[base];
        }
    }
    #pragma unroll
    for (int kt = 0; kt < NKT; ++kt) {
        const int cur = kt & 1, nxt = cur ^ 1;
        if (kt + 1 < NKT) {
            #pragma unroll
            for (int c = 0; c < 3; ++c) {
                int ct = wv + 8 * c;
                if (ct < 19) {
                    unsigned base = ((unsigned)((kt + 1) * 19 + ct) * 64u + lane) * 8u;
                    pbhi[nxt][c] = *(const bf16x8v*)&whi[base];
                    pblo[nxt][c] = *(const bf16x8v*)&wlo[base];
                }
            }
        }
        #pragma unroll
        for (int rt = 0; rt < 4; ++rt) {
            bf16x8v a = *(const bf16x8v*)&As[(rt * 16 + cr) * LDK + kt * 32 + quad * 8];
            #pragma unroll
            for (int c = 0; c < 3; ++c) {
                int ct = wv + 8 * c;
                if (ct >= 19) break;
                acc[rt][c] = __builtin_amdgcn_mfma_f32_16x16x32_bf16(a, pblo[cur][c], acc[rt][c], 0, 0, 0);
                acc[rt][c] = __builtin_amdgcn_mfma_f32_16x16x32_bf16(a, pbhi[cur][c], acc[rt][c], 0, 0, 0);
            }
        }
    }
    __syncthreads();
    #pragma unroll
    for (int c = 0; c < 3; ++c) {
        int ct = wv + 8 * c;
        if (ct >= 19) break;
        int col = ct * 16 + cr;
        if (col >= 300) continue;
        #pragma unroll
        for (int rt = 0; rt < 4; ++rt)
            #pragma unroll
            for (int r = 0; r < 4; ++r) {
                float v = acc[rt][c][r];
                As[(rt * 16 + quad * 4 + r) * LDK + col] = f2bf_us(RELU ? fmaxf(v, 0.f) : v);
            }
    }
    __syncthreads();
    for (int idx = tid; idx < 64 * 75; idx += 512) {
        int r = idx / 75, q = idx - r * 75;
        *(ushort4*)&out_rows[(unsigned)(n0 + r) * 300u + q * 4] = *(const ushort4*)&As[r * LDK + q * 4];
    }
}

// ---------------- mp GEMM: h[e] = relu(h[e] + (inc[src[e]] - h[rev(e)]) @ W + b) ----------------
// 64 rows = 32 pairs / block. Stage computes Hs[r] = inc[src]-h[pair] AND tees the raw
// pair-h bf16 into Hs2[r^32] (= own-row h), so the epilogue's +h[e] reads LDS instead
// of 94 MB of scalar 2B col-strided global loads. LDS ~80.6 KB/block (2 blocks/CU,
// same as before; >64KB static LDS proven by r7's au at 77KB).
__global__ __launch_bounds__(768, 6) void k_mp_mfma(
        unsigned short* __restrict__ h, const unsigned short* __restrict__ inc,
        const int* __restrict__ srcH, const int* __restrict__ dstH,
        const unsigned short* __restrict__ whi, const unsigned short* __restrict__ wlo,
        const float* __restrict__ bias) {
    constexpr int LDK = 328;
    __shared__ unsigned short Hs[64 * LDK];
    __shared__ unsigned short Hs2[64 * 300];   // own-row h, teed during stage
    __shared__ int ssrc[64];
    const int tid = threadIdx.x;
    const int lane = tid & 63, wv = tid >> 6;
    const int quad = lane >> 4, cr = lane & 15;
    const int p0 = blockIdx.x * 32;
    if (tid < 64) {
        int r = tid;
        int e = (r < 32) ? (p0 + r) : (p0 + r - 32 + HALF);
        int s = (e < HALF) ? srcH[e] : dstH[e - HALF];
        ssrc[r] = clampi(s, 0, NN - 1);
    }
    __syncthreads();
    // single-pass operand staging: Hs[r] = inc[src[e_r]] - h[pair(e_r)], zero-pad to KP=320.
    // The pair-h raw bits ARE own-row r^32's h -> tee into Hs2 for the epilogue.
    for (int idx = tid; idx < 64 * 80; idx += 768) {
        int r = idx / 80, q = idx - r * 80;
        int col = q * 4;
        if (col < 300) {
            unsigned ep = (r < 32) ? (unsigned)(p0 + r + HALF) : (unsigned)(p0 + r - 32);
            ushort4 hu = *(const ushort4*)&h[ep * 300u + col];
            float4 hp = make_float4(bf2f_us(hu.x), bf2f_us(hu.y), bf2f_us(hu.z), bf2f_us(hu.w));
            float4 iv = ld4(&inc[(unsigned)ssrc[r] * 300u + col]);
            st4(&Hs[r * LDK + col],
                make_float4(iv.x - hp.x, iv.y - hp.y, iv.z - hp.z, iv.w - hp.w));
            *(ushort4*)&Hs2[(r ^ 32) * 300 + col] = hu;
        } else {
            *(ushort4*)&Hs[r * LDK + col] = make_ushort4(0, 0, 0, 0);
        }
    }
    __syncthreads();
    f32x4v acc[4][2];
    #pragma unroll
    for (int c = 0; c < 2; ++c)
        #pragma unroll
        for (int rt = 0; rt < 4; ++rt) {
            f32x4v a = {0.f, 0.f, 0.f, 0.f};
            acc[rt][c] = a;
        }
    for (int kt = 0; kt < 10; ++kt) {
        bf16x8v bb[2];
        #pragma unroll
        for (int c = 0; c < 2; ++c) {
            int ct = wv + 12 * c;
            if (ct < 19)
                bb[c] = *(const bf16x8v*)&wlo[((unsigned)(kt * 19 + ct) * 64u + lane) * 8u];
        }
        #pragma unroll
        for (int rt = 0; rt < 4; ++rt) {
            bf16x8v a = *(const bf16x8v*)&Hs[(rt * 16 + cr) * LDK + kt * 32 + quad * 8];
            #pragma unroll
            for (int c = 0; c < 2; ++c) {
                int ct = wv + 12 * c;
                if (ct >= 19) break;
                acc[rt][c] = __builtin_amdgcn_mfma_f32_16x16x32_bf16(a, bb[c], acc[rt][c], 0, 0, 0);
            }
        }
        #pragma unroll
        for (int c = 0; c < 2; ++c) {
            int ct = wv + 12 * c;
            if (ct < 19)
                bb[c] = *(const bf16x8v*)&whi[((unsigned)(kt * 19 + ct) * 64u + lane) * 8u];
        }
        #pragma unroll
        for (int rt = 0; rt < 4; ++rt) {
            bf16x8v a = *(const bf16x8v*)&Hs[(rt * 16 + cr) * LDK + kt * 32 + quad * 8];
            #pragma unroll
            for (int c = 0; c < 2; ++c) {
                int ct = wv + 12 * c;
                if (ct >= 19) break;
                acc[rt][c] = __builtin_amdgcn_mfma_f32_16x16x32_bf16(a, bb[c], acc[rt][c], 0, 0, 0);
            }
        }
    }
    __syncthreads();   // all GEMM reads of Hs done before epilogue overwrites
    #pragma unroll
    for (int c = 0; c < 2; ++c) {
        int ct = wv + 12 * c;
        if (ct >= 19) break;
        int col = ct * 16 + cr;
        if (col >= 300) continue;
        float bv = bias[col];
        #pragma unroll
        for (int rt = 0; rt < 4; ++rt)
            #pragma unroll
            for (int r = 0; r < 4; ++r) {
                int row = rt * 16 + quad * 4 + r;
                float hv = bf2f_us(Hs2[row * 300 + col]);   // own-row h from LDS
                Hs[row * LDK + col] = f2bf_us(fmaxf(acc[rt][c][r] + bv + hv, 0.f));
            }
    }
    __syncthreads();
    for (int idx = tid; idx < 64 * 75; idx += 768) {
        int r = idx / 75, q = idx - r * 75;
        unsigned e = (r < 32) ? (unsigned)(p0 + r) : (unsigned)(p0 + r - 32 + HALF);
        *(ushort4*)&h[e * 300u + q * 4] = *(const ushort4*)&Hs[r * LDK + q * 4];
    }
}

// ---------------- pooling (bf16 rows) + reparam ----------------
__global__ __launch_bounds__(320) void k_pool(const unsigned short* __restrict__ rows,
                                              const float* __restrict__ wat,
                                              const int* __restrict__ gs, float* __restrict__ outg) {
    int g = blockIdx.x, c = threadIdx.x;
    if (c >= 300) return;
    int lo = clampi(gs[g], 0, NN), hi = clampi(gs[g + 1], 0, NN);
    float acc = 0.f;
    for (int n = lo; n < hi; ++n)
        acc += bf2f_us(rows[(unsigned)n * 300u + c]) * wat[n];
    float cn = fmaxf((float)(hi - lo), 1.f);
    outg[g * 300 + c] = acc / cn;
}
__global__ __launch_bounds__(320) void k_final(const float* __restrict__ mu_g, const float* __restrict__ lv_g,
                                               const float* __restrict__ eps, float* __restrict__ out) {
    int g = blockIdx.x, c = threadIdx.x;
    if (c >= 300) return;
    out[g * 300 + c] = mu_g[g * 300 + c] + expf(0.5f * lv_g[g * 300 + c]) * eps[g * 300 + c];
}

extern "C" void kernel_launch(void* const* d_in, const int* in_sizes, int n_in,
                              void* d_out, int out_size, void* d_ws, size_t ws_size,
                              hipStream_t stream) {
    float* outp = (float*)d_out;

    const size_t NEED = 199500000ull;   // carve ~199.43 MB; ws proven >= 200,000,000
    if (ws_size < NEED) {
        k_zerof<<<(out_size + 255) / 256, 256, 0, stream>>>(outp, out_size);
        return;
    }

    const float* x   = (const float*)d_in[0];
    const float* ea  = (const float*)d_in[1];
    const float* wat = (const float*)d_in[2];
    const float* eps = (const float*)d_in[3];
    const int* srcH  = (const int*)d_in[4];
    const int* dstH  = (const int*)d_in[5];
    const int* batch = (const int*)d_in[6];
    const float* w_t_lin  = (const float*)d_in[7];
    const float* b_t_lin  = (const float*)d_in[8];
    const float* w_t_mp   = (const float*)d_in[9];
    const float* b_t_mp   = (const float*)d_in[10];
    const float* w_t_au   = (const float*)d_in[11];
    const float* b_t_au   = (const float*)d_in[12];
    const float* w_mu_lin = (const float*)d_in[13];
    const float* b_mu_lin = (const float*)d_in[14];
    const float* w_mu_mp  = (const float*)d_in[15];
    const float* b_mu_mp  = (const float*)d_in[16];
    const float* w_mu_au  = (const float*)d_in[17];
    const float* b_mu_au  = (const float*)d_in[18];
    const float* w_lv_lin = (const float*)d_in[19];
    const float* b_lv_lin = (const float*)d_in[20];
    const float* w_lv_mp  = (const float*)d_in[21];
    const float* b_lv_mp  = (const float*)d_in[22];
    const float* w_lv_au  = (const float*)d_in[23];
    const float* b_lv_au  = (const float*)d_in[24];

    char* p = (char*)d_ws;
    auto alloc = [&](size_t nbytes) { char* q = p; p += (nbytes + 255) & ~(size_t)255; return q; };
    unsigned short* h   = (unsigned short*)alloc((size_t)NE * 300 * 2);   // 96 MB
    unsigned short* inc = (unsigned short*)alloc((size_t)NN * 300 * 2);   // 48 MB (segsum result)
    unsigned short* sh  = (unsigned short*)alloc((size_t)NN * 300 * 2);   // 48 MB
    const size_t MPU = (size_t)3 * 10 * 19 * 512;   // mp tables (ushorts)
    unsigned short* wh_mp = (unsigned short*)alloc(MPU * 2);
    unsigned short* wl_mp = (unsigned short*)alloc(MPU * 2);
    const size_t LAU = (size_t)29 * 19 * 512;       // lin+au tables
    unsigned short* wh_la = (unsigned short*)alloc(LAU * 2);
    unsigned short* wl_la = (unsigned short*)alloc(LAU * 2);
    float* mu_g = (float*)alloc((size_t)NG * 300 * 4);
    float* lv_g = (float*)alloc((size_t)NG * 300 * 4);
    int* deg    = (int*)alloc(NN * 4);               // reused as cursor (alias-safe)
    int* startA = (int*)alloc((NN + 1) * 4);
    int* elist  = (int*)alloc(NE * 4);
    int* degg   = (int*)alloc(NG * 4);
    int* gs     = (int*)alloc((NG + 1) * 4);
    int* part   = (int*)alloc(SCB * 4);

    // ---- CSR (incoming by dst), multi-block scan; cursor aliases deg ----
    k_zeroi<<<(NN + 255) / 256, 256, 0, stream>>>(deg, NN);
    k_hist<<<(NE + 255) / 256, 256, 0, stream>>>(srcH, dstH, deg);
    k_scan_part<<<SCB, 256, 0, stream>>>(deg, part, NN);
    k_scan_offsets<<<1, 256, 0, stream>>>(part);
    k_scan_apply<<<SCB, 256, 0, stream>>>(deg, part, startA, deg, NN);
    k_fill<<<(NE + 255) / 256, 256, 0, stream>>>(srcH, dstH, deg, elist);
    // ---- graph-CSR over sorted batch ----
    k_zeroi<<<(NG + 255) / 256, 256, 0, stream>>>(degg, NG);
    k_histg<<<(NN + 255) / 256, 256, 0, stream>>>(batch, degg);
    k_scan_part<<<SCB, 256, 0, stream>>>(degg, part, NG);
    k_scan_offsets<<<1, 256, 0, stream>>>(part);
    k_scan_apply<<<SCB, 256, 0, stream>>>(degg, part, gs, (int*)nullptr, NG);

    const int SSG = (NN * 38 + 255) / 256;
    const size_t MP_L = (size_t)10 * 19 * 512;      // ushorts per mp layer
    auto wsplit_conv = [&](const float* Wmp, const float* Wlin, int Klin, int nktlin,
                           const float* Wau, int Kau, int nktau) {
        int total = 570 + nktlin * 19 + nktau * 19;
        k_wsplit_conv<<<(total * 64 + 255) / 256, 256, 0, stream>>>(
            Wmp, Wlin, Klin, nktlin, Wau, Kau, nktau, wh_mp, wl_mp, wh_la, wl_la);
    };

    // ================= conv t =================
    wsplit_conv(w_t_mp, w_t_lin, 147, 5, w_t_au, 433, 14);
    const size_t AU_T = (size_t)5 * 19 * 512;
    k_lin_mfma<133, float><<<NE / 64, 768, 0, stream>>>(x, ea, srcH, dstH, wh_la, wl_la, b_t_lin, h);
    for (int i = 0; i < 3; ++i) {
        k_segsum8<<<SSG, 256, 0, stream>>>(h, elist, startA, inc);
        k_mp_mfma<<<HALF / 32, 768, 0, stream>>>(h, inc, srcH, dstH,
                                                 wh_mp + i * MP_L, wl_mp + i * MP_L, b_t_mp + i * 300);
    }
    // de-fused au: segsum first (streaming, roofline), then fully dense au GEMM
    k_segsum8<<<SSG, 256, 0, stream>>>(h, elist, startA, inc);
    k_au_mfma<133, float, true><<<NN / 64, 512, 0, stream>>>(x, inc,
                                                             wh_la + AU_T, wl_la + AU_T, b_t_au, sh);

    // ================= conv mu =================
    wsplit_conv(w_mu_mp, w_mu_lin, 314, 10, w_mu_au, 600, 19);
    const size_t AU_MU = (size_t)10 * 19 * 512;
    k_lin_mfma<300, unsigned short><<<NE / 64, 768, 0, stream>>>(sh, ea, srcH, dstH, wh_la, wl_la, b_mu_lin, h);
    for (int i = 0; i < 3; ++i) {
        k_segsum8<<<SSG, 256, 0, stream>>>(h, elist, startA, inc);
        k_mp_mfma<<<HALF / 32, 768, 0, stream>>>(h, inc, srcH, dstH,
                                                 wh_mp + i * MP_L, wl_mp + i * MP_L, b_mu_mp + i * 300);
    }
    // de-fused au: after this segsum, h is DEAD (au reads only sh + inc) -> au output
    // lives in the h buffer's first 48 MB; pool consumes it before lv's lin rewrites h.
    k_segsum8<<<SSG, 256, 0, stream>>>(h, elist, startA, inc);
    {
        unsigned short* rows = h;
        k_au_mfma<300, unsigned short, false><<<NN / 64, 512, 0, stream>>>(sh, inc,
                                                                           wh_la + AU_MU, wl_la + AU_MU, b_mu_au, rows);
        k_pool<<<NG, 320, 0, stream>>>(rows, wat, gs, mu_g);
    }

    // ================= conv lv =================
    wsplit_conv(w_lv_mp, w_lv_lin, 314, 10, w_lv_au, 600, 19);
    k_lin_mfma<300, unsigned short><<<NE / 64, 768, 0, stream>>>(sh, ea, srcH, dstH, wh_la, wl_la, b_lv_lin, h);
    for (int i = 0; i < 3; ++i) {
        k_segsum8<<<SSG, 256, 0, stream>>>(h, elist, startA, inc);
        k_mp_mfma<<<HALF / 32, 768, 0, stream>>>(h, inc, srcH, dstH,
                                                 wh_mp + i * MP_L, wl_mp + i * MP_L, b_lv_mp + i * 300);
    }
    k_segsum8<<<SSG, 256, 0, stream>>>(h, elist, startA, inc);
    {
        unsigned short* rows = h;
        k_au_mfma<300, unsigned short, false><<<NN / 64, 512, 0, stream>>>(sh, inc,
                                                                           wh_la + AU_MU, wl_la + AU_MU, b_lv_au, rows);
        k_pool<<<NG, 320, 0, stream>>>(rows, wat, gs, lv_g);
    }

    // ---- reparam ----
    k_final<<<NG, 320, 0, stream>>>(mu_g, lv_g, eps, outp);
}

// Round 10
// 1905.221 us; speedup vs baseline: 1.0799x; 1.0155x over previous
//
#include <hip/hip_runtime.h>
#include <hip/hip_bf16.h>

#define NN 80000       // nodes
#define NE 160000      // edges (both directions)
#define HALF 80000
#define HID 300
#define NG 1600
#define SCB 256        // scan blocks

typedef __attribute__((ext_vector_type(8))) short bf16x8v;
typedef __attribute__((ext_vector_type(4))) float f32x4v;

// ---------------- helpers ----------------
__device__ __forceinline__ float bf2f_us(unsigned short u) {
    return __uint_as_float(((unsigned int)u) << 16);
}
// native RNE convert: lowers to v_cvt_pk_bf16_f32 on gfx950
__device__ __forceinline__ unsigned short f2bf_us(float f) {
    union { __bf16 b; unsigned short u; } cv;
    cv.b = (__bf16)f;
    return cv.u;
}
__device__ __forceinline__ float ld1(const float* p) { return *p; }
__device__ __forceinline__ float ld1(const unsigned short* p) { return bf2f_us(*p); }
__device__ __forceinline__ float4 ld4(const float* p) { return *(const float4*)p; }
__device__ __forceinline__ float4 ld4(const unsigned short* p) {
    ushort4 u = *(const ushort4*)p;
    return make_float4(bf2f_us(u.x), bf2f_us(u.y), bf2f_us(u.z), bf2f_us(u.w));
}
__device__ __forceinline__ void st4(float* p, float4 v) { *(float4*)p = v; }
__device__ __forceinline__ void st4(unsigned short* p, float4 v) {
    ushort4 u; u.x = f2bf_us(v.x); u.y = f2bf_us(v.y); u.z = f2bf_us(v.z); u.w = f2bf_us(v.w);
    *(ushort4*)p = u;
}
__device__ __forceinline__ int clampi(int v, int lo, int hi) {
    return v < lo ? lo : (v > hi ? hi : v);
}

// ---------------- zero-fill ----------------
__global__ void k_zerof(float* __restrict__ p, int n) {
    int i = blockIdx.x * 256 + threadIdx.x; if (i < n) p[i] = 0.f;
}
__global__ void k_zeroi(int* __restrict__ p, int n) {
    int i = blockIdx.x * 256 + threadIdx.x; if (i < n) p[i] = 0;
}

// ---------------- merged per-conv W split: mp(3 layers) + lin + au in ONE dispatch ----------------
// fragment order per tile t: lane holds B[k=kt*32+quad*8+j][n=ct*16+(lane&15)], j=0..7
__global__ void k_wsplit_conv(const float* __restrict__ Wmp,
                              const float* __restrict__ Wlin, int Klin, int nktlin,
                              const float* __restrict__ Wau, int Kau, int nktau,
                              unsigned short* __restrict__ wh_mp, unsigned short* __restrict__ wl_mp,
                              unsigned short* __restrict__ wh_la, unsigned short* __restrict__ wl_la) {
    const int MP_L = 10 * 19 * 512;   // ushorts per mp layer
    int idx = blockIdx.x * 256 + threadIdx.x;
    int total = 570 + nktlin * 19 + nktau * 19;
    int t = idx >> 6;
    if (t >= total) return;
    int lane = idx & 63;
    const float* W; int Krows, ltile;
    unsigned short *whi, *wlo;
    if (t < 570) {                       // mp: 3 layers x 190 tiles
        int l = t / 190, rem = t - l * 190;
        W = Wmp + l * 90000; Krows = 300; ltile = rem;
        whi = wh_mp + l * MP_L; wlo = wl_mp + l * MP_L;
    } else if (t < 570 + nktlin * 19) {  // lin at la offset 0
        ltile = t - 570; W = Wlin; Krows = Klin;
        whi = wh_la; wlo = wl_la;
    } else {                             // au after lin tiles
        ltile = t - 570 - nktlin * 19; W = Wau; Krows = Kau;
        size_t off = (size_t)nktlin * 19 * 512;
        whi = wh_la + off; wlo = wl_la + off;
    }
    int kt = ltile / 19, ct = ltile - kt * 19;
    int quad = lane >> 4, cr = lane & 15;
    unsigned obase = ((unsigned)ltile * 64u + lane) * 8u;
    for (int j = 0; j < 8; ++j) {
        int k = kt * 32 + quad * 8 + j;
        int n = ct * 16 + cr;
        float v = (k < Krows && n < 300) ? W[(unsigned)k * 300u + n] : 0.f;
        unsigned short hu = f2bf_us(v);
        unsigned short lu = f2bf_us(v - bf2f_us(hu));
        whi[obase + j] = hu;
        wlo[obase + j] = lu;
    }
}

// ---------------- CSR build ----------------
__global__ void k_hist(const int* __restrict__ srcH, const int* __restrict__ dstH, int* __restrict__ deg) {
    int e = blockIdx.x * 256 + threadIdx.x;
    if (e >= NE) return;
    int d = (e < HALF) ? dstH[e] : srcH[e - HALF];
    d = clampi(d, 0, NN - 1);
    atomicAdd(&deg[d], 1);
}
__global__ void k_histg(const int* __restrict__ batch, int* __restrict__ degg) {
    int n = blockIdx.x * 256 + threadIdx.x;
    if (n >= NN) return;
    atomicAdd(&degg[clampi(batch[n], 0, NG - 1)], 1);
}

// ---------------- 3-phase multi-block exclusive scan ----------------
__global__ __launch_bounds__(256) void k_scan_part(const int* __restrict__ deg, int* __restrict__ part, int n) {
    __shared__ int red[256];
    int b = blockIdx.x, t = threadIdx.x;
    int chunk = (n + SCB - 1) / SCB;
    int lo = b * chunk, hi = lo + chunk; if (hi > n) hi = n;
    int s = 0;
    for (int i = lo + t; i < hi; i += 256) s += deg[i];
    red[t] = s;
    __syncthreads();
    for (int off = 128; off > 0; off >>= 1) {
        if (t < off) red[t] += red[t + off];
        __syncthreads();
    }
    if (t == 0) part[b] = red[0];
}
__global__ __launch_bounds__(256) void k_scan_offsets(int* __restrict__ part) {
    __shared__ int sh[256];
    int t = threadIdx.x;
    sh[t] = part[t];
    __syncthreads();
    for (int off = 1; off < 256; off <<= 1) {
        int v = (t >= off) ? sh[t - off] : 0;
        __syncthreads();
        sh[t] += v;
        __syncthreads();
    }
    part[t] = (t == 0) ? 0 : sh[t - 1];
}
__global__ __launch_bounds__(256) void k_scan_apply(const int* __restrict__ deg, const int* __restrict__ part,
                                                    int* __restrict__ start, int* cursor, int n) {
    __shared__ int sh[256];
    int b = blockIdx.x, t = threadIdx.x;
    int chunk = (n + SCB - 1) / SCB;
    int lo = b * chunk, hi = lo + chunk; if (hi > n) hi = n;
    int sub = (chunk + 255) / 256;
    int slo = lo + t * sub, shi = slo + sub;
    if (slo > hi) slo = hi;
    if (shi > hi) shi = hi;
    int s = 0;
    for (int i = slo; i < shi; ++i) s += deg[i];
    sh[t] = s;
    __syncthreads();
    for (int off = 1; off < 256; off <<= 1) {
        int v = (t >= off) ? sh[t - off] : 0;
        __syncthreads();
        sh[t] += v;
        __syncthreads();
    }
    int run = part[b] + sh[t] - s;
    for (int i = slo; i < shi; ++i) {
        int d = deg[i];              // read before aliased cursor write
        start[i] = run;
        if (cursor) cursor[i] = run;
        run += d;
    }
    if (b == SCB - 1 && t == 255) start[n] = run;
}

__global__ void k_fill(const int* __restrict__ srcH, const int* __restrict__ dstH,
                       int* __restrict__ cursor, int* __restrict__ elist) {
    int e = blockIdx.x * 256 + threadIdx.x;
    if (e >= NE) return;
    int d = (e < HALF) ? dstH[e] : srcH[e - HALF];
    d = clampi(d, 0, NN - 1);
    int pos = atomicAdd(&cursor[d], 1);
    if (pos >= 0 && pos < NE) elist[pos] = e;
}

// ---------------- segment sum: thread per (node, 8-col group) ----------------
// Measured at ~5.3 TB/s (gather roofline). Feeds mp and the de-fused au.
__global__ __launch_bounds__(256) void k_segsum8(const unsigned short* __restrict__ h,
                                                 const int* __restrict__ elist,
                                                 const int* __restrict__ start,
                                                 unsigned short* __restrict__ inc) {
    int t = blockIdx.x * 256 + threadIdx.x;
    if (t >= NN * 38) return;
    int n = t / 38, q = t - n * 38;
    int c0 = q * 8;
    bool full = (c0 + 8 <= 300);
    int lo = clampi(start[n], 0, NE), hi = clampi(start[n + 1], 0, NE);
    float4 a0 = make_float4(0.f, 0.f, 0.f, 0.f);
    float4 a1 = make_float4(0.f, 0.f, 0.f, 0.f);
    int j = lo;
    for (; j + 2 <= hi; j += 2) {
        unsigned e0 = (unsigned)clampi(elist[j], 0, NE - 1);
        unsigned e1 = (unsigned)clampi(elist[j + 1], 0, NE - 1);
        const unsigned short* r0 = &h[e0 * 300u + c0];
        const unsigned short* r1 = &h[e1 * 300u + c0];
        float4 v0 = ld4(r0);
        float4 w0 = ld4(r1);
        a0.x += v0.x + w0.x; a0.y += v0.y + w0.y; a0.z += v0.z + w0.z; a0.w += v0.w + w0.w;
        if (full) {
            float4 v1 = ld4(r0 + 4);
            float4 w1 = ld4(r1 + 4);
            a1.x += v1.x + w1.x; a1.y += v1.y + w1.y; a1.z += v1.z + w1.z; a1.w += v1.w + w1.w;
        }
    }
    if (j < hi) {
        unsigned e0 = (unsigned)clampi(elist[j], 0, NE - 1);
        const unsigned short* r0 = &h[e0 * 300u + c0];
        float4 v0 = ld4(r0);
        a0.x += v0.x; a0.y += v0.y; a0.z += v0.z; a0.w += v0.w;
        if (full) {
            float4 v1 = ld4(r0 + 4);
            a1.x += v1.x; a1.y += v1.y; a1.z += v1.z; a1.w += v1.w;
        }
    }
    st4(&inc[(unsigned)n * 300u + c0], a0);
    if (full) st4(&inc[(unsigned)n * 300u + c0 + 4], a1);
}

// ================= GEMM core =================
// lin/mp/au: 768 threads = 12 waves over a 64-row tile; wave w owns ct = w + 12c
// (c<2). Single-buffered weights (prefetch dbuf proven neutral r2). mp keeps the
// r9 LDS-tee (epilogue +h from Hs2). au is the r8 dense de-fused form, now also
// 12-wave: LDS 78.8 KB x 2 blocks = 157.7 KB fits -> 24 waves/CU (was 16).

// ---------------- lin GEMM: h[e] = relu(concat(node_in[src[e]], ea[e]) @ W + b) ----------------
template <int NID, typename TN>
__global__ __launch_bounds__(768, 6) void k_lin_mfma(
        const TN* __restrict__ node_in, const float* __restrict__ ea,
        const int* __restrict__ srcH, const int* __restrict__ dstH,
        const unsigned short* __restrict__ whi, const unsigned short* __restrict__ wlo,
        const float* __restrict__ bias, unsigned short* __restrict__ h) {
    constexpr int K = NID + 14;
    constexpr int KP = (K + 31) & ~31;                    // 160 or 320
    constexpr int NKT = KP / 32;
    constexpr int LDK = (KP + 8 < 312) ? 312 : KP + 8;
    __shared__ unsigned short As[64 * LDK];
    __shared__ int ssrc[64];
    const int tid = threadIdx.x;
    const int lane = tid & 63, wv = tid >> 6;
    const int quad = lane >> 4, cr = lane & 15;
    const int e0 = blockIdx.x * 64;
    if (tid < 64) {
        int e = e0 + tid;
        int s = (e < HALF) ? srcH[e] : dstH[e - HALF];
        ssrc[tid] = clampi(s, 0, NN - 1);
    }
    __syncthreads();
    if constexpr (NID == 300) {
        for (int idx = tid; idx < 64 * 75; idx += 768) {
            int r = idx / 75, q = idx - r * 75;
            *(ushort4*)&As[r * LDK + q * 4] =
                *(const ushort4*)&((const unsigned short*)node_in)[(unsigned)ssrc[r] * 300u + q * 4];
        }
        for (int idx = tid; idx < 64 * (KP - 300); idx += 768) {
            int r = idx / (KP - 300), k = idx - r * (KP - 300);
            int kk = 300 + k;
            float v = (kk < K) ? ea[(unsigned)(e0 + r) * 14u + (kk - 300)] : 0.f;
            As[r * LDK + kk] = f2bf_us(v);
        }
    } else {
        for (int idx = tid; idx < 64 * KP; idx += 768) {
            int r = idx / KP, k = idx - r * KP;
            float v;
            if (k < NID)    v = ld1(&node_in[(unsigned)ssrc[r] * (unsigned)NID + k]);
            else if (k < K) v = ea[(unsigned)(e0 + r) * 14u + (k - NID)];
            else            v = 0.f;
            As[r * LDK + k] = f2bf_us(v);
        }
    }
    __syncthreads();
    f32x4v acc[4][2];
    #pragma unroll
    for (int c = 0; c < 2; ++c) {
        int ct = wv + 12 * c;
        float b = 0.f;
        if (ct < 19) { int col = ct * 16 + cr; if (col < 300) b = bias[col]; }
        #pragma unroll
        for (int rt = 0; rt < 4; ++rt) { f32x4v a = {b, b, b, b}; acc[rt][c] = a; }
    }
    for (int kt = 0; kt < NKT; ++kt) {
        bf16x8v bb[2];
        #pragma unroll
        for (int c = 0; c < 2; ++c) {
            int ct = wv + 12 * c;
            if (ct < 19)
                bb[c] = *(const bf16x8v*)&wlo[((unsigned)(kt * 19 + ct) * 64u + lane) * 8u];
        }
        #pragma unroll
        for (int rt = 0; rt < 4; ++rt) {
            bf16x8v a = *(const bf16x8v*)&As[(rt * 16 + cr) * LDK + kt * 32 + quad * 8];
            #pragma unroll
            for (int c = 0; c < 2; ++c) {
                int ct = wv + 12 * c;
                if (ct >= 19) break;
                acc[rt][c] = __builtin_amdgcn_mfma_f32_16x16x32_bf16(a, bb[c], acc[rt][c], 0, 0, 0);
            }
        }
        #pragma unroll
        for (int c = 0; c < 2; ++c) {
            int ct = wv + 12 * c;
            if (ct < 19)
                bb[c] = *(const bf16x8v*)&whi[((unsigned)(kt * 19 + ct) * 64u + lane) * 8u];
        }
        #pragma unroll
        for (int rt = 0; rt < 4; ++rt) {
            bf16x8v a = *(const bf16x8v*)&As[(rt * 16 + cr) * LDK + kt * 32 + quad * 8];
            #pragma unroll
            for (int c = 0; c < 2; ++c) {
                int ct = wv + 12 * c;
                if (ct >= 19) break;
                acc[rt][c] = __builtin_amdgcn_mfma_f32_16x16x32_bf16(a, bb[c], acc[rt][c], 0, 0, 0);
            }
        }
    }
    __syncthreads();
    #pragma unroll
    for (int c = 0; c < 2; ++c) {
        int ct = wv + 12 * c;
        if (ct >= 19) break;
        int col = ct * 16 + cr;
        if (col >= 300) continue;
        #pragma unroll
        for (int rt = 0; rt < 4; ++rt)
            #pragma unroll
            for (int r = 0; r < 4; ++r)
                As[(rt * 16 + quad * 4 + r) * LDK + col] = f2bf_us(fmaxf(acc[rt][c][r], 0.f));
    }
    __syncthreads();
    for (int idx = tid; idx < 64 * 75; idx += 768) {
        int r = idx / 75, q = idx - r * 75;
        *(ushort4*)&h[(unsigned)(e0 + r) * 300u + q * 4] = *(const ushort4*)&As[r * LDK + q * 4];
    }
}

// ---------------- au GEMM (DENSE, de-fused, 12-wave): out[n] = (relu?)(concat(node_in[n], inc[n]) @ W + b) ----
template <int NID, typename TN, bool RELU>
__global__ __launch_bounds__(768, 6) void k_au_mfma(
        const TN* __restrict__ node_in, const unsigned short* __restrict__ inc,
        const unsigned short* __restrict__ whi, const unsigned short* __restrict__ wlo,
        const float* __restrict__ bias, unsigned short* __restrict__ out_rows) {
    constexpr int K = NID + 300;
    constexpr int KP = (K + 31) & ~31;     // 448 or 608
    constexpr int NKT = KP / 32;
    constexpr int LDK = KP + 8;            // 456 / 616
    __shared__ unsigned short As[64 * LDK];
    const int tid = threadIdx.x;
    const int lane = tid & 63, wv = tid >> 6;
    const int quad = lane >> 4, cr = lane & 15;
    const int n0 = blockIdx.x * 64;
    // node part: cols [0, NID) — dense
    if constexpr (NID == 300) {
        for (int idx = tid; idx < 64 * 75; idx += 768) {
            int r = idx / 75, q = idx - r * 75;
            *(ushort4*)&As[r * LDK + q * 4] =
                *(const ushort4*)&((const unsigned short*)node_in)[(unsigned)(n0 + r) * 300u + q * 4];
        }
    } else {
        // contiguous 64-row fp32 block: flat aligned float4 copy (64*NID divisible by 4 for NID=133)
        const float* xb = (const float*)node_in + (size_t)n0 * NID;
        for (int f4 = tid; f4 < (64 * NID) / 4; f4 += 768) {
            float4 v = *(const float4*)&xb[f4 * 4];
            int f = f4 * 4;
            float vv[4] = {v.x, v.y, v.z, v.w};
            #pragma unroll
            for (int i = 0; i < 4; ++i) {
                int fi = f + i;
                int r = fi / NID, k = fi - r * NID;
                As[r * LDK + k] = f2bf_us(vv[i]);
            }
        }
    }
    // seg part: cols [NID, NID+300) — dense copy of inc rows (NO gather)
    if constexpr (NID == 300) {
        for (int idx = tid; idx < 64 * 75; idx += 768) {
            int r = idx / 75, q = idx - r * 75;
            *(ushort4*)&As[r * LDK + 300 + q * 4] =
                *(const ushort4*)&inc[(unsigned)(n0 + r) * 300u + q * 4];
        }
    } else {
        // NID=133 odd -> LDS dest misaligned for ushort4; aligned global load + scalar LDS stores
        for (int idx = tid; idx < 64 * 75; idx += 768) {
            int r = idx / 75, q = idx - r * 75;
            ushort4 v = *(const ushort4*)&inc[(unsigned)(n0 + r) * 300u + q * 4];
            unsigned short* dst = &As[r * LDK + NID + q * 4];
            dst[0] = v.x; dst[1] = v.y; dst[2] = v.z; dst[3] = v.w;
        }
    }
    // pad: cols [NID+300, KP)
    constexpr int PAD = KP - NID - 300;
    for (int idx = tid; idx < 64 * PAD; idx += 768) {
        int r = idx / PAD, k = idx - r * PAD;
        As[r * LDK + NID + 300 + k] = 0;
    }
    __syncthreads();
    f32x4v acc[4][2];
    #pragma unroll
    for (int c = 0; c < 2; ++c) {
        int ct = wv + 12 * c;
        float b = 0.f;
        if (ct < 19) { int col = ct * 16 + cr; if (col < 300) b = bias[col]; }
        #pragma unroll
        for (int rt = 0; rt < 4; ++rt) { f32x4v a = {b, b, b, b}; acc[rt][c] = a; }
    }
    for (int kt = 0; kt < NKT; ++kt) {
        bf16x8v bb[2];
        #pragma unroll
        for (int c = 0; c < 2; ++c) {
            int ct = wv + 12 * c;
            if (ct < 19)
                bb[c] = *(const bf16x8v*)&wlo[((unsigned)(kt * 19 + ct) * 64u + lane) * 8u];
        }
        #pragma unroll
        for (int rt = 0; rt < 4; ++rt) {
            bf16x8v a = *(const bf16x8v*)&As[(rt * 16 + cr) * LDK + kt * 32 + quad * 8];
            #pragma unroll
            for (int c = 0; c < 2; ++c) {
                int ct = wv + 12 * c;
                if (ct >= 19) break;
                acc[rt][c] = __builtin_amdgcn_mfma_f32_16x16x32_bf16(a, bb[c], acc[rt][c], 0, 0, 0);
            }
        }
        #pragma unroll
        for (int c = 0; c < 2; ++c) {
            int ct = wv + 12 * c;
            if (ct < 19)
                bb[c] = *(const bf16x8v*)&whi[((unsigned)(kt * 19 + ct) * 64u + lane) * 8u];
        }
        #pragma unroll
        for (int rt = 0; rt < 4; ++rt) {
            bf16x8v a = *(const bf16x8v*)&As[(rt * 16 + cr) * LDK + kt * 32 + quad * 8];
            #pragma unroll
            for (int c = 0; c < 2; ++c) {
                int ct = wv + 12 * c;
                if (ct >= 19) break;
                acc[rt][c] = __builtin_amdgcn_mfma_f32_16x16x32_bf16(a, bb[c], acc[rt][c], 0, 0, 0);
            }
        }
    }
    __syncthreads();
    #pragma unroll
    for (int c = 0; c < 2; ++c) {
        int ct = wv + 12 * c;
        if (ct >= 19) break;
        int col = ct * 16 + cr;
        if (col >= 300) continue;
        #pragma unroll
        for (int rt = 0; rt < 4; ++rt)
            #pragma unroll
            for (int r = 0; r < 4; ++r) {
                float v = acc[rt][c][r];
                As[(rt * 16 + quad * 4 + r) * LDK + col] = f2bf_us(RELU ? fmaxf(v, 0.f) : v);
            }
    }
    __syncthreads();
    for (int idx = tid; idx < 64 * 75; idx += 768) {
        int r = idx / 75, q = idx - r * 75;
        *(ushort4*)&out_rows[(unsigned)(n0 + r) * 300u + q * 4] = *(const ushort4*)&As[r * LDK + q * 4];
    }
}

// ---------------- mp GEMM: h[e] = relu(h[e] + (inc[src[e]] - h[rev(e)]) @ W + b) ----------------
// r9 form (proven 103us): stage computes Hs[r] = inc[src]-h[pair] AND tees the raw
// pair-h bf16 into Hs2[r^32] (= own-row h) so the epilogue's +h[e] reads LDS.
__global__ __launch_bounds__(768, 6) void k_mp_mfma(
        unsigned short* __restrict__ h, const unsigned short* __restrict__ inc,
        const int* __restrict__ srcH, const int* __restrict__ dstH,
        const unsigned short* __restrict__ whi, const unsigned short* __restrict__ wlo,
        const float* __restrict__ bias) {
    constexpr int LDK = 328;
    __shared__ unsigned short Hs[64 * LDK];
    __shared__ unsigned short Hs2[64 * 300];   // own-row h, teed during stage
    __shared__ int ssrc[64];
    const int tid = threadIdx.x;
    const int lane = tid & 63, wv = tid >> 6;
    const int quad = lane >> 4, cr = lane & 15;
    const int p0 = blockIdx.x * 32;
    if (tid < 64) {
        int r = tid;
        int e = (r < 32) ? (p0 + r) : (p0 + r - 32 + HALF);
        int s = (e < HALF) ? srcH[e] : dstH[e - HALF];
        ssrc[r] = clampi(s, 0, NN - 1);
    }
    __syncthreads();
    // single-pass operand staging: Hs[r] = inc[src[e_r]] - h[pair(e_r)], zero-pad to KP=320.
    // The pair-h raw bits ARE own-row r^32's h -> tee into Hs2 for the epilogue.
    for (int idx = tid; idx < 64 * 80; idx += 768) {
        int r = idx / 80, q = idx - r * 80;
        int col = q * 4;
        if (col < 300) {
            unsigned ep = (r < 32) ? (unsigned)(p0 + r + HALF) : (unsigned)(p0 + r - 32);
            ushort4 hu = *(const ushort4*)&h[ep * 300u + col];
            float4 hp = make_float4(bf2f_us(hu.x), bf2f_us(hu.y), bf2f_us(hu.z), bf2f_us(hu.w));
            float4 iv = ld4(&inc[(unsigned)ssrc[r] * 300u + col]);
            st4(&Hs[r * LDK + col],
                make_float4(iv.x - hp.x, iv.y - hp.y, iv.z - hp.z, iv.w - hp.w));
            *(ushort4*)&Hs2[(r ^ 32) * 300 + col] = hu;
        } else {
            *(ushort4*)&Hs[r * LDK + col] = make_ushort4(0, 0, 0, 0);
        }
    }
    __syncthreads();
    f32x4v acc[4][2];
    #pragma unroll
    for (int c = 0; c < 2; ++c)
        #pragma unroll
        for (int rt = 0; rt < 4; ++rt) {
            f32x4v a = {0.f, 0.f, 0.f, 0.f};
            acc[rt][c] = a;
        }
    for (int kt = 0; kt < 10; ++kt) {
        bf16x8v bb[2];
        #pragma unroll
        for (int c = 0; c < 2; ++c) {
            int ct = wv + 12 * c;
            if (ct < 19)
                bb[c] = *(const bf16x8v*)&wlo[((unsigned)(kt * 19 + ct) * 64u + lane) * 8u];
        }
        #pragma unroll
        for (int rt = 0; rt < 4; ++rt) {
            bf16x8v a = *(const bf16x8v*)&Hs[(rt * 16 + cr) * LDK + kt * 32 + quad * 8];
            #pragma unroll
            for (int c = 0; c < 2; ++c) {
                int ct = wv + 12 * c;
                if (ct >= 19) break;
                acc[rt][c] = __builtin_amdgcn_mfma_f32_16x16x32_bf16(a, bb[c], acc[rt][c], 0, 0, 0);
            }
        }
        #pragma unroll
        for (int c = 0; c < 2; ++c) {
            int ct = wv + 12 * c;
            if (ct < 19)
                bb[c] = *(const bf16x8v*)&whi[((unsigned)(kt * 19 + ct) * 64u + lane) * 8u];
        }
        #pragma unroll
        for (int rt = 0; rt < 4; ++rt) {
            bf16x8v a = *(const bf16x8v*)&Hs[(rt * 16 + cr) * LDK + kt * 32 + quad * 8];
            #pragma unroll
            for (int c = 0; c < 2; ++c) {
                int ct = wv + 12 * c;
                if (ct >= 19) break;
                acc[rt][c] = __builtin_amdgcn_mfma_f32_16x16x32_bf16(a, bb[c], acc[rt][c], 0, 0, 0);
            }
        }
    }
    __syncthreads();   // all GEMM reads of Hs done before epilogue overwrites
    #pragma unroll
    for (int c = 0; c < 2; ++c) {
        int ct = wv + 12 * c;
        if (ct >= 19) break;
        int col = ct * 16 + cr;
        if (col >= 300) continue;
        float bv = bias[col];
        #pragma unroll
        for (int rt = 0; rt < 4; ++rt)
            #pragma unroll
            for (int r = 0; r < 4; ++r) {
                int row = rt * 16 + quad * 4 + r;
                float hv = bf2f_us(Hs2[row * 300 + col]);   // own-row h from LDS
                Hs[row * LDK + col] = f2bf_us(fmaxf(acc[rt][c][r] + bv + hv, 0.f));
            }
    }
    __syncthreads();
    for (int idx = tid; idx < 64 * 75; idx += 768) {
        int r = idx / 75, q = idx - r * 75;
        unsigned e = (r < 32) ? (unsigned)(p0 + r) : (unsigned)(p0 + r - 32 + HALF);
        *(ushort4*)&h[e * 300u + q * 4] = *(const ushort4*)&Hs[r * LDK + q * 4];
    }
}

// ---------------- pooling (bf16 rows, 2x unrolled sequential adds) + reparam ----------------
__global__ __launch_bounds__(320) void k_pool(const unsigned short* __restrict__ rows,
                                              const float* __restrict__ wat,
                                              const int* __restrict__ gs, float* __restrict__ outg) {
    int g = blockIdx.x, c = threadIdx.x;
    if (c >= 300) return;
    int lo = clampi(gs[g], 0, NN), hi = clampi(gs[g + 1], 0, NN);
    float acc = 0.f;
    int n = lo;
    for (; n + 2 <= hi; n += 2) {
        float v0 = bf2f_us(rows[(unsigned)n * 300u + c]) * wat[n];
        float v1 = bf2f_us(rows[(unsigned)(n + 1) * 300u + c]) * wat[n + 1];
        acc += v0;           // sequential adds: identical order to the scalar loop
        acc += v1;
    }
    if (n < hi)
        acc += bf2f_us(rows[(unsigned)n * 300u + c]) * wat[n];
    float cn = fmaxf((float)(hi - lo), 1.f);
    outg[g * 300 + c] = acc / cn;
}
__global__ __launch_bounds__(320) void k_final(const float* __restrict__ mu_g, const float* __restrict__ lv_g,
                                               const float* __restrict__ eps, float* __restrict__ out) {
    int g = blockIdx.x, c = threadIdx.x;
    if (c >= 300) return;
    out[g * 300 + c] = mu_g[g * 300 + c] + expf(0.5f * lv_g[g * 300 + c]) * eps[g * 300 + c];
}

extern "C" void kernel_launch(void* const* d_in, const int* in_sizes, int n_in,
                              void* d_out, int out_size, void* d_ws, size_t ws_size,
                              hipStream_t stream) {
    float* outp = (float*)d_out;

    const size_t NEED = 199500000ull;   // carve ~199.43 MB; ws proven >= 200,000,000
    if (ws_size < NEED) {
        k_zerof<<<(out_size + 255) / 256, 256, 0, stream>>>(outp, out_size);
        return;
    }

    const float* x   = (const float*)d_in[0];
    const float* ea  = (const float*)d_in[1];
    const float* wat = (const float*)d_in[2];
    const float* eps = (const float*)d_in[3];
    const int* srcH  = (const int*)d_in[4];
    const int* dstH  = (const int*)d_in[5];
    const int* batch = (const int*)d_in[6];
    const float* w_t_lin  = (const float*)d_in[7];
    const float* b_t_lin  = (const float*)d_in[8];
    const float* w_t_mp   = (const float*)d_in[9];
    const float* b_t_mp   = (const float*)d_in[10];
    const float* w_t_au   = (const float*)d_in[11];
    const float* b_t_au   = (const float*)d_in[12];
    const float* w_mu_lin = (const float*)d_in[13];
    const float* b_mu_lin = (const float*)d_in[14];
    const float* w_mu_mp  = (const float*)d_in[15];
    const float* b_mu_mp  = (const float*)d_in[16];
    const float* w_mu_au  = (const float*)d_in[17];
    const float* b_mu_au  = (const float*)d_in[18];
    const float* w_lv_lin = (const float*)d_in[19];
    const float* b_lv_lin = (const float*)d_in[20];
    const float* w_lv_mp  = (const float*)d_in[21];
    const float* b_lv_mp  = (const float*)d_in[22];
    const float* w_lv_au  = (const float*)d_in[23];
    const float* b_lv_au  = (const float*)d_in[24];

    char* p = (char*)d_ws;
    auto alloc = [&](size_t nbytes) { char* q = p; p += (nbytes + 255) & ~(size_t)255; return q; };
    unsigned short* h   = (unsigned short*)alloc((size_t)NE * 300 * 2);   // 96 MB
    unsigned short* inc = (unsigned short*)alloc((size_t)NN * 300 * 2);   // 48 MB (segsum result)
    unsigned short* sh  = (unsigned short*)alloc((size_t)NN * 300 * 2);   // 48 MB
    const size_t MPU = (size_t)3 * 10 * 19 * 512;   // mp tables (ushorts)
    unsigned short* wh_mp = (unsigned short*)alloc(MPU * 2);
    unsigned short* wl_mp = (unsigned short*)alloc(MPU * 2);
    const size_t LAU = (size_t)29 * 19 * 512;       // lin+au tables
    unsigned short* wh_la = (unsigned short*)alloc(LAU * 2);
    unsigned short* wl_la = (unsigned short*)alloc(LAU * 2);
    float* mu_g = (float*)alloc((size_t)NG * 300 * 4);
    float* lv_g = (float*)alloc((size_t)NG * 300 * 4);
    int* deg    = (int*)alloc(NN * 4);               // reused as cursor (alias-safe)
    int* startA = (int*)alloc((NN + 1) * 4);
    int* elist  = (int*)alloc(NE * 4);
    int* degg   = (int*)alloc(NG * 4);
    int* gs     = (int*)alloc((NG + 1) * 4);
    int* part   = (int*)alloc(SCB * 4);

    // ---- CSR (incoming by dst), multi-block scan; cursor aliases deg ----
    k_zeroi<<<(NN + 255) / 256, 256, 0, stream>>>(deg, NN);
    k_hist<<<(NE + 255) / 256, 256, 0, stream>>>(srcH, dstH, deg);
    k_scan_part<<<SCB, 256, 0, stream>>>(deg, part, NN);
    k_scan_offsets<<<1, 256, 0, stream>>>(part);
    k_scan_apply<<<SCB, 256, 0, stream>>>(deg, part, startA, deg, NN);
    k_fill<<<(NE + 255) / 256, 256, 0, stream>>>(srcH, dstH, deg, elist);
    // ---- graph-CSR over sorted batch ----
    k_zeroi<<<(NG + 255) / 256, 256, 0, stream>>>(degg, NG);
    k_histg<<<(NN + 255) / 256, 256, 0, stream>>>(batch, degg);
    k_scan_part<<<SCB, 256, 0, stream>>>(degg, part, NG);
    k_scan_offsets<<<1, 256, 0, stream>>>(part);
    k_scan_apply<<<SCB, 256, 0, stream>>>(degg, part, gs, (int*)nullptr, NG);

    const int SSG = (NN * 38 + 255) / 256;
    const size_t MP_L = (size_t)10 * 19 * 512;      // ushorts per mp layer
    auto wsplit_conv = [&](const float* Wmp, const float* Wlin, int Klin, int nktlin,
                           const float* Wau, int Kau, int nktau) {
        int total = 570 + nktlin * 19 + nktau * 19;
        k_wsplit_conv<<<(total * 64 + 255) / 256, 256, 0, stream>>>(
            Wmp, Wlin, Klin, nktlin, Wau, Kau, nktau, wh_mp, wl_mp, wh_la, wl_la);
    };

    // ================= conv t =================
    wsplit_conv(w_t_mp, w_t_lin, 147, 5, w_t_au, 433, 14);
    const size_t AU_T = (size_t)5 * 19 * 512;
    k_lin_mfma<133, float><<<NE / 64, 768, 0, stream>>>(x, ea, srcH, dstH, wh_la, wl_la, b_t_lin, h);
    for (int i = 0; i < 3; ++i) {
        k_segsum8<<<SSG, 256, 0, stream>>>(h, elist, startA, inc);
        k_mp_mfma<<<HALF / 32, 768, 0, stream>>>(h, inc, srcH, dstH,
                                                 wh_mp + i * MP_L, wl_mp + i * MP_L, b_t_mp + i * 300);
    }
    // de-fused au: segsum first (streaming, roofline), then fully dense au GEMM
    k_segsum8<<<SSG, 256, 0, stream>>>(h, elist, startA, inc);
    k_au_mfma<133, float, true><<<NN / 64, 768, 0, stream>>>(x, inc,
                                                             wh_la + AU_T, wl_la + AU_T, b_t_au, sh);

    // ================= conv mu =================
    wsplit_conv(w_mu_mp, w_mu_lin, 314, 10, w_mu_au, 600, 19);
    const size_t AU_MU = (size_t)10 * 19 * 512;
    k_lin_mfma<300, unsigned short><<<NE / 64, 768, 0, stream>>>(sh, ea, srcH, dstH, wh_la, wl_la, b_mu_lin, h);
    for (int i = 0; i < 3; ++i) {
        k_segsum8<<<SSG, 256, 0, stream>>>(h, elist, startA, inc);
        k_mp_mfma<<<HALF / 32, 768, 0, stream>>>(h, inc, srcH, dstH,
                                                 wh_mp + i * MP_L, wl_mp + i * MP_L, b_mu_mp + i * 300);
    }
    // de-fused au: after this segsum, h is DEAD (au reads only sh + inc) -> au output
    // lives in the h buffer's first 48 MB; pool consumes it before lv's lin rewrites h.
    k_segsum8<<<SSG, 256, 0, stream>>>(h, elist, startA, inc);
    {
        unsigned short* rows = h;
        k_au_mfma<300, unsigned short, false><<<NN / 64, 768, 0, stream>>>(sh, inc,
                                                                           wh_la + AU_MU, wl_la + AU_MU, b_mu_au, rows);
        k_pool<<<NG, 320, 0, stream>>>(rows, wat, gs, mu_g);
    }

    // ================= conv lv =================
    wsplit_conv(w_lv_mp, w_lv_lin, 314, 10, w_lv_au, 600, 19);
    k_lin_mfma<300, unsigned short><<<NE / 64, 768, 0, stream>>>(sh, ea, srcH, dstH, wh_la, wl_la, b_lv_lin, h);
    for (int i = 0; i < 3; ++i) {
        k_segsum8<<<SSG, 256, 0, stream>>>(h, elist, startA, inc);
        k_mp_mfma<<<HALF / 32, 768, 0, stream>>>(h, inc, srcH, dstH,
                                                 wh_mp + i * MP_L, wl_mp + i * MP_L, b_lv_mp + i * 300);
    }
    k_segsum8<<<SSG, 256, 0, stream>>>(h, elist, startA, inc);
    {
        unsigned short* rows = h;
        k_au_mfma<300, unsigned short, false><<<NN / 64, 768, 0, stream>>>(sh, inc,
                                                                           wh_la + AU_MU, wl_la + AU_MU, b_lv_au, rows);
        k_pool<<<NG, 320, 0, stream>>>(rows, wat, gs, lv_g);
    }

    // ---- reparam ----
    k_final<<<NG, 320, 0, stream>>>(mu_g, lv_g, eps, outp);
}

// Round 11
// 1901.406 us; speedup vs baseline: 1.0821x; 1.0020x over previous
//
#include <hip/hip_runtime.h>
#include <hip/hip_bf16.h>

#define NN 80000       // nodes
#define NE 160000      // edges (both directions)
#define HALF 80000
#define HID 300
#define NG 1600
#define SCB 256        // scan blocks

typedef __attribute__((ext_vector_type(8))) short bf16x8v;
typedef __attribute__((ext_vector_type(4))) float f32x4v;

// ---------------- helpers ----------------
__device__ __forceinline__ float bf2f_us(unsigned short u) {
    return __uint_as_float(((unsigned int)u) << 16);
}
// native RNE convert: lowers to v_cvt_pk_bf16_f32 on gfx950
__device__ __forceinline__ unsigned short f2bf_us(float f) {
    union { __bf16 b; unsigned short u; } cv;
    cv.b = (__bf16)f;
    return cv.u;
}
__device__ __forceinline__ float ld1(const float* p) { return *p; }
__device__ __forceinline__ float ld1(const unsigned short* p) { return bf2f_us(*p); }
__device__ __forceinline__ float4 ld4(const float* p) { return *(const float4*)p; }
__device__ __forceinline__ float4 ld4(const unsigned short* p) {
    ushort4 u = *(const ushort4*)p;
    return make_float4(bf2f_us(u.x), bf2f_us(u.y), bf2f_us(u.z), bf2f_us(u.w));
}
__device__ __forceinline__ void st4(float* p, float4 v) { *(float4*)p = v; }
__device__ __forceinline__ void st4(unsigned short* p, float4 v) {
    ushort4 u; u.x = f2bf_us(v.x); u.y = f2bf_us(v.y); u.z = f2bf_us(v.z); u.w = f2bf_us(v.w);
    *(ushort4*)p = u;
}
// 16B bf16 row-segment helpers (same values/order as 8 scalar converts; half the loads)
__device__ __forceinline__ void bf8_to_f(uint4 raw, float* f) {
    f[0] = __uint_as_float(raw.x << 16); f[1] = __uint_as_float(raw.x & 0xffff0000u);
    f[2] = __uint_as_float(raw.y << 16); f[3] = __uint_as_float(raw.y & 0xffff0000u);
    f[4] = __uint_as_float(raw.z << 16); f[5] = __uint_as_float(raw.z & 0xffff0000u);
    f[6] = __uint_as_float(raw.w << 16); f[7] = __uint_as_float(raw.w & 0xffff0000u);
}
__device__ __forceinline__ uint4 f8_to_bf(const float* f) {
    uint4 r;
    r.x = (unsigned)f2bf_us(f[0]) | ((unsigned)f2bf_us(f[1]) << 16);
    r.y = (unsigned)f2bf_us(f[2]) | ((unsigned)f2bf_us(f[3]) << 16);
    r.z = (unsigned)f2bf_us(f[4]) | ((unsigned)f2bf_us(f[5]) << 16);
    r.w = (unsigned)f2bf_us(f[6]) | ((unsigned)f2bf_us(f[7]) << 16);
    return r;
}
__device__ __forceinline__ int clampi(int v, int lo, int hi) {
    return v < lo ? lo : (v > hi ? hi : v);
}

// ---------------- zero-fill ----------------
__global__ void k_zerof(float* __restrict__ p, int n) {
    int i = blockIdx.x * 256 + threadIdx.x; if (i < n) p[i] = 0.f;
}
__global__ void k_zeroi(int* __restrict__ p, int n) {
    int i = blockIdx.x * 256 + threadIdx.x; if (i < n) p[i] = 0;
}

// ---------------- merged per-conv W split: mp(3 layers) + lin + au in ONE dispatch ----------------
// fragment order per tile t: lane holds B[k=kt*32+quad*8+j][n=ct*16+(lane&15)], j=0..7
__global__ void k_wsplit_conv(const float* __restrict__ Wmp,
                              const float* __restrict__ Wlin, int Klin, int nktlin,
                              const float* __restrict__ Wau, int Kau, int nktau,
                              unsigned short* __restrict__ wh_mp, unsigned short* __restrict__ wl_mp,
                              unsigned short* __restrict__ wh_la, unsigned short* __restrict__ wl_la) {
    const int MP_L = 10 * 19 * 512;   // ushorts per mp layer
    int idx = blockIdx.x * 256 + threadIdx.x;
    int total = 570 + nktlin * 19 + nktau * 19;
    int t = idx >> 6;
    if (t >= total) return;
    int lane = idx & 63;
    const float* W; int Krows, ltile;
    unsigned short *whi, *wlo;
    if (t < 570) {                       // mp: 3 layers x 190 tiles
        int l = t / 190, rem = t - l * 190;
        W = Wmp + l * 90000; Krows = 300; ltile = rem;
        whi = wh_mp + l * MP_L; wlo = wl_mp + l * MP_L;
    } else if (t < 570 + nktlin * 19) {  // lin at la offset 0
        ltile = t - 570; W = Wlin; Krows = Klin;
        whi = wh_la; wlo = wl_la;
    } else {                             // au after lin tiles
        ltile = t - 570 - nktlin * 19; W = Wau; Krows = Kau;
        size_t off = (size_t)nktlin * 19 * 512;
        whi = wh_la + off; wlo = wl_la + off;
    }
    int kt = ltile / 19, ct = ltile - kt * 19;
    int quad = lane >> 4, cr = lane & 15;
    unsigned obase = ((unsigned)ltile * 64u + lane) * 8u;
    for (int j = 0; j < 8; ++j) {
        int k = kt * 32 + quad * 8 + j;
        int n = ct * 16 + cr;
        float v = (k < Krows && n < 300) ? W[(unsigned)k * 300u + n] : 0.f;
        unsigned short hu = f2bf_us(v);
        unsigned short lu = f2bf_us(v - bf2f_us(hu));
        whi[obase + j] = hu;
        wlo[obase + j] = lu;
    }
}

// ---------------- CSR build ----------------
__global__ void k_hist(const int* __restrict__ srcH, const int* __restrict__ dstH, int* __restrict__ deg) {
    int e = blockIdx.x * 256 + threadIdx.x;
    if (e >= NE) return;
    int d = (e < HALF) ? dstH[e] : srcH[e - HALF];
    d = clampi(d, 0, NN - 1);
    atomicAdd(&deg[d], 1);
}
__global__ void k_histg(const int* __restrict__ batch, int* __restrict__ degg) {
    int n = blockIdx.x * 256 + threadIdx.x;
    if (n >= NN) return;
    atomicAdd(&degg[clampi(batch[n], 0, NG - 1)], 1);
}

// ---------------- 3-phase multi-block exclusive scan ----------------
__global__ __launch_bounds__(256) void k_scan_part(const int* __restrict__ deg, int* __restrict__ part, int n) {
    __shared__ int red[256];
    int b = blockIdx.x, t = threadIdx.x;
    int chunk = (n + SCB - 1) / SCB;
    int lo = b * chunk, hi = lo + chunk; if (hi > n) hi = n;
    int s = 0;
    for (int i = lo + t; i < hi; i += 256) s += deg[i];
    red[t] = s;
    __syncthreads();
    for (int off = 128; off > 0; off >>= 1) {
        if (t < off) red[t] += red[t + off];
        __syncthreads();
    }
    if (t == 0) part[b] = red[0];
}
__global__ __launch_bounds__(256) void k_scan_offsets(int* __restrict__ part) {
    __shared__ int sh[256];
    int t = threadIdx.x;
    sh[t] = part[t];
    __syncthreads();
    for (int off = 1; off < 256; off <<= 1) {
        int v = (t >= off) ? sh[t - off] : 0;
        __syncthreads();
        sh[t] += v;
        __syncthreads();
    }
    part[t] = (t == 0) ? 0 : sh[t - 1];
}
__global__ __launch_bounds__(256) void k_scan_apply(const int* __restrict__ deg, const int* __restrict__ part,
                                                    int* __restrict__ start, int* cursor, int n) {
    __shared__ int sh[256];
    int b = blockIdx.x, t = threadIdx.x;
    int chunk = (n + SCB - 1) / SCB;
    int lo = b * chunk, hi = lo + chunk; if (hi > n) hi = n;
    int sub = (chunk + 255) / 256;
    int slo = lo + t * sub, shi = slo + sub;
    if (slo > hi) slo = hi;
    if (shi > hi) shi = hi;
    int s = 0;
    for (int i = slo; i < shi; ++i) s += deg[i];
    sh[t] = s;
    __syncthreads();
    for (int off = 1; off < 256; off <<= 1) {
        int v = (t >= off) ? sh[t - off] : 0;
        __syncthreads();
        sh[t] += v;
        __syncthreads();
    }
    int run = part[b] + sh[t] - s;
    for (int i = slo; i < shi; ++i) {
        int d = deg[i];              // read before aliased cursor write
        start[i] = run;
        if (cursor) cursor[i] = run;
        run += d;
    }
    if (b == SCB - 1 && t == 255) start[n] = run;
}

__global__ void k_fill(const int* __restrict__ srcH, const int* __restrict__ dstH,
                       int* __restrict__ cursor, int* __restrict__ elist) {
    int e = blockIdx.x * 256 + threadIdx.x;
    if (e >= NE) return;
    int d = (e < HALF) ? dstH[e] : srcH[e - HALF];
    d = clampi(d, 0, NN - 1);
    int pos = atomicAdd(&cursor[d], 1);
    if (pos >= 0 && pos < NE) elist[pos] = e;
}

// ---------------- segment sum: thread per (node, 8-col group), 16B gathered loads ----------------
__global__ __launch_bounds__(256) void k_segsum8(const unsigned short* __restrict__ h,
                                                 const int* __restrict__ elist,
                                                 const int* __restrict__ start,
                                                 unsigned short* __restrict__ inc) {
    int t = blockIdx.x * 256 + threadIdx.x;
    if (t >= NN * 38) return;
    int n = t / 38, q = t - n * 38;
    int c0 = q * 8;
    bool full = (c0 + 8 <= 300);
    int lo = clampi(start[n], 0, NE), hi = clampi(start[n + 1], 0, NE);
    float4 a0 = make_float4(0.f, 0.f, 0.f, 0.f);
    float4 a1 = make_float4(0.f, 0.f, 0.f, 0.f);
    int j = lo;
    for (; j + 2 <= hi; j += 2) {
        unsigned e0 = (unsigned)clampi(elist[j], 0, NE - 1);
        unsigned e1 = (unsigned)clampi(elist[j + 1], 0, NE - 1);
        if (full) {
            uint4 r0 = *(const uint4*)&h[e0 * 300u + c0];
            uint4 r1 = *(const uint4*)&h[e1 * 300u + c0];
            float f0[8], f1[8];
            bf8_to_f(r0, f0); bf8_to_f(r1, f1);
            a0.x += f0[0] + f1[0]; a0.y += f0[1] + f1[1]; a0.z += f0[2] + f1[2]; a0.w += f0[3] + f1[3];
            a1.x += f0[4] + f1[4]; a1.y += f0[5] + f1[5]; a1.z += f0[6] + f1[6]; a1.w += f0[7] + f1[7];
        } else {
            float4 v0 = ld4(&h[e0 * 300u + c0]);
            float4 w0 = ld4(&h[e1 * 300u + c0]);
            a0.x += v0.x + w0.x; a0.y += v0.y + w0.y; a0.z += v0.z + w0.z; a0.w += v0.w + w0.w;
        }
    }
    if (j < hi) {
        unsigned e0 = (unsigned)clampi(elist[j], 0, NE - 1);
        if (full) {
            uint4 r0 = *(const uint4*)&h[e0 * 300u + c0];
            float f0[8];
            bf8_to_f(r0, f0);
            a0.x += f0[0]; a0.y += f0[1]; a0.z += f0[2]; a0.w += f0[3];
            a1.x += f0[4]; a1.y += f0[5]; a1.z += f0[6]; a1.w += f0[7];
        } else {
            float4 v0 = ld4(&h[e0 * 300u + c0]);
            a0.x += v0.x; a0.y += v0.y; a0.z += v0.z; a0.w += v0.w;
        }
    }
    st4(&inc[(unsigned)n * 300u + c0], a0);
    if (full) st4(&inc[(unsigned)n * 300u + c0 + 4], a1);
}

// ================= GEMM core =================
// lin/mp/au: 768 threads = 12 waves over a 64-row tile; wave w owns ct = w + 12c (c<2).
// Round-11: all gather phases use 16B loads (half the issued VMEM instrs); mp keeps
// the r9 LDS-tee; au is the r8 dense de-fused form (12-wave).

// ---------------- lin GEMM: h[e] = relu(concat(node_in[src[e]], ea[e]) @ W + b) ----------------
template <int NID, typename TN>
__global__ __launch_bounds__(768, 6) void k_lin_mfma(
        const TN* __restrict__ node_in, const float* __restrict__ ea,
        const int* __restrict__ srcH, const int* __restrict__ dstH,
        const unsigned short* __restrict__ whi, const unsigned short* __restrict__ wlo,
        const float* __restrict__ bias, unsigned short* __restrict__ h) {
    constexpr int K = NID + 14;
    constexpr int KP = (K + 31) & ~31;                    // 160 or 320
    constexpr int NKT = KP / 32;
    constexpr int LDK = (KP + 8 < 312) ? 312 : KP + 8;    // 312 or 328 (both 16B-aligned rows)
    __shared__ __align__(16) unsigned short As[64 * LDK];
    __shared__ int ssrc[64];
    const int tid = threadIdx.x;
    const int lane = tid & 63, wv = tid >> 6;
    const int quad = lane >> 4, cr = lane & 15;
    const int e0 = blockIdx.x * 64;
    if (tid < 64) {
        int e = e0 + tid;
        int s = (e < HALF) ? srcH[e] : dstH[e - HALF];
        ssrc[tid] = clampi(s, 0, NN - 1);
    }
    __syncthreads();
    if constexpr (NID == 300) {
        // 16B row gather: cols 0-295 (37 groups), tail 296-299
        for (int idx = tid; idx < 64 * 37; idx += 768) {
            int r = idx / 37, q = idx - r * 37;
            *(uint4*)&As[r * LDK + q * 8] =
                *(const uint4*)&((const unsigned short*)node_in)[(unsigned)ssrc[r] * 300u + q * 8];
        }
        for (int idx = tid; idx < 64; idx += 768) {
            int r = idx;
            *(ushort4*)&As[r * LDK + 296] =
                *(const ushort4*)&((const unsigned short*)node_in)[(unsigned)ssrc[r] * 300u + 296];
        }
        for (int idx = tid; idx < 64 * (KP - 300); idx += 768) {
            int r = idx / (KP - 300), k = idx - r * (KP - 300);
            int kk = 300 + k;
            float v = (kk < K) ? ea[(unsigned)(e0 + r) * 14u + (kk - 300)] : 0.f;
            As[r * LDK + kk] = f2bf_us(v);
        }
    } else {
        // NID=133 fp32: float4 row gather (cols 0-131), tail col 132 + ea + pad
        for (int idx = tid; idx < 64 * 34; idx += 768) {
            int r = idx / 34, q = idx - r * 34;
            if (q < 33) {
                float4 v = *(const float4*)&((const float*)node_in)[(unsigned)ssrc[r] * 133u + q * 4];
                ushort4 u;
                u.x = f2bf_us(v.x); u.y = f2bf_us(v.y); u.z = f2bf_us(v.z); u.w = f2bf_us(v.w);
                *(ushort4*)&As[r * LDK + q * 4] = u;
            } else {
                float last = ((const float*)node_in)[(unsigned)ssrc[r] * 133u + 132];
                As[r * LDK + 132] = f2bf_us(last);
                #pragma unroll
                for (int k = 0; k < 14; ++k)
                    As[r * LDK + 133 + k] = f2bf_us(ea[(unsigned)(e0 + r) * 14u + k]);
                #pragma unroll
                for (int k = 147; k < 160; ++k)
                    As[r * LDK + k] = 0;
            }
        }
    }
    __syncthreads();
    f32x4v acc[4][2];
    #pragma unroll
    for (int c = 0; c < 2; ++c) {
        int ct = wv + 12 * c;
        float b = 0.f;
        if (ct < 19) { int col = ct * 16 + cr; if (col < 300) b = bias[col]; }
        #pragma unroll
        for (int rt = 0; rt < 4; ++rt) { f32x4v a = {b, b, b, b}; acc[rt][c] = a; }
    }
    for (int kt = 0; kt < NKT; ++kt) {
        bf16x8v bb[2];
        #pragma unroll
        for (int c = 0; c < 2; ++c) {
            int ct = wv + 12 * c;
            if (ct < 19)
                bb[c] = *(const bf16x8v*)&wlo[((unsigned)(kt * 19 + ct) * 64u + lane) * 8u];
        }
        #pragma unroll
        for (int rt = 0; rt < 4; ++rt) {
            bf16x8v a = *(const bf16x8v*)&As[(rt * 16 + cr) * LDK + kt * 32 + quad * 8];
            #pragma unroll
            for (int c = 0; c < 2; ++c) {
                int ct = wv + 12 * c;
                if (ct >= 19) break;
                acc[rt][c] = __builtin_amdgcn_mfma_f32_16x16x32_bf16(a, bb[c], acc[rt][c], 0, 0, 0);
            }
        }
        #pragma unroll
        for (int c = 0; c < 2; ++c) {
            int ct = wv + 12 * c;
            if (ct < 19)
                bb[c] = *(const bf16x8v*)&whi[((unsigned)(kt * 19 + ct) * 64u + lane) * 8u];
        }
        #pragma unroll
        for (int rt = 0; rt < 4; ++rt) {
            bf16x8v a = *(const bf16x8v*)&As[(rt * 16 + cr) * LDK + kt * 32 + quad * 8];
            #pragma unroll
            for (int c = 0; c < 2; ++c) {
                int ct = wv + 12 * c;
                if (ct >= 19) break;
                acc[rt][c] = __builtin_amdgcn_mfma_f32_16x16x32_bf16(a, bb[c], acc[rt][c], 0, 0, 0);
            }
        }
    }
    __syncthreads();
    #pragma unroll
    for (int c = 0; c < 2; ++c) {
        int ct = wv + 12 * c;
        if (ct >= 19) break;
        int col = ct * 16 + cr;
        if (col >= 300) continue;
        #pragma unroll
        for (int rt = 0; rt < 4; ++rt)
            #pragma unroll
            for (int r = 0; r < 4; ++r)
                As[(rt * 16 + quad * 4 + r) * LDK + col] = f2bf_us(fmaxf(acc[rt][c][r], 0.f));
    }
    __syncthreads();
    for (int idx = tid; idx < 64 * 75; idx += 768) {
        int r = idx / 75, q = idx - r * 75;
        *(ushort4*)&h[(unsigned)(e0 + r) * 300u + q * 4] = *(const ushort4*)&As[r * LDK + q * 4];
    }
}

// ---------------- au GEMM (DENSE, de-fused, 12-wave): out[n] = (relu?)(concat(node_in[n], inc[n]) @ W + b) ----
template <int NID, typename TN, bool RELU>
__global__ __launch_bounds__(768, 6) void k_au_mfma(
        const TN* __restrict__ node_in, const unsigned short* __restrict__ inc,
        const unsigned short* __restrict__ whi, const unsigned short* __restrict__ wlo,
        const float* __restrict__ bias, unsigned short* __restrict__ out_rows) {
    constexpr int K = NID + 300;
    constexpr int KP = (K + 31) & ~31;     // 448 or 608
    constexpr int NKT = KP / 32;
    constexpr int LDK = KP + 8;            // 456 / 616
    __shared__ __align__(16) unsigned short As[64 * LDK];
    const int tid = threadIdx.x;
    const int lane = tid & 63, wv = tid >> 6;
    const int quad = lane >> 4, cr = lane & 15;
    const int n0 = blockIdx.x * 64;
    // node part: cols [0, NID) — dense
    if constexpr (NID == 300) {
        for (int idx = tid; idx < 64 * 75; idx += 768) {
            int r = idx / 75, q = idx - r * 75;
            *(ushort4*)&As[r * LDK + q * 4] =
                *(const ushort4*)&((const unsigned short*)node_in)[(unsigned)(n0 + r) * 300u + q * 4];
        }
    } else {
        // contiguous 64-row fp32 block: flat aligned float4 copy (64*NID divisible by 4 for NID=133)
        const float* xb = (const float*)node_in + (size_t)n0 * NID;
        for (int f4 = tid; f4 < (64 * NID) / 4; f4 += 768) {
            float4 v = *(const float4*)&xb[f4 * 4];
            int f = f4 * 4;
            float vv[4] = {v.x, v.y, v.z, v.w};
            #pragma unroll
            for (int i = 0; i < 4; ++i) {
                int fi = f + i;
                int r = fi / NID, k = fi - r * NID;
                As[r * LDK + k] = f2bf_us(vv[i]);
            }
        }
    }
    // seg part: cols [NID, NID+300) — dense copy of inc rows (NO gather)
    if constexpr (NID == 300) {
        for (int idx = tid; idx < 64 * 75; idx += 768) {
            int r = idx / 75, q = idx - r * 75;
            *(ushort4*)&As[r * LDK + 300 + q * 4] =
                *(const ushort4*)&inc[(unsigned)(n0 + r) * 300u + q * 4];
        }
    } else {
        // NID=133 odd -> LDS dest misaligned for ushort4; aligned global load + scalar LDS stores
        for (int idx = tid; idx < 64 * 75; idx += 768) {
            int r = idx / 75, q = idx - r * 75;
            ushort4 v = *(const ushort4*)&inc[(unsigned)(n0 + r) * 300u + q * 4];
            unsigned short* dst = &As[r * LDK + NID + q * 4];
            dst[0] = v.x; dst[1] = v.y; dst[2] = v.z; dst[3] = v.w;
        }
    }
    // pad: cols [NID+300, KP)
    constexpr int PAD = KP - NID - 300;
    for (int idx = tid; idx < 64 * PAD; idx += 768) {
        int r = idx / PAD, k = idx - r * PAD;
        As[r * LDK + NID + 300 + k] = 0;
    }
    __syncthreads();
    f32x4v acc[4][2];
    #pragma unroll
    for (int c = 0; c < 2; ++c) {
        int ct = wv + 12 * c;
        float b = 0.f;
        if (ct < 19) { int col = ct * 16 + cr; if (col < 300) b = bias[col]; }
        #pragma unroll
        for (int rt = 0; rt < 4; ++rt) { f32x4v a = {b, b, b, b}; acc[rt][c] = a; }
    }
    for (int kt = 0; kt < NKT; ++kt) {
        bf16x8v bb[2];
        #pragma unroll
        for (int c = 0; c < 2; ++c) {
            int ct = wv + 12 * c;
            if (ct < 19)
                bb[c] = *(const bf16x8v*)&wlo[((unsigned)(kt * 19 + ct) * 64u + lane) * 8u];
        }
        #pragma unroll
        for (int rt = 0; rt < 4; ++rt) {
            bf16x8v a = *(const bf16x8v*)&As[(rt * 16 + cr) * LDK + kt * 32 + quad * 8];
            #pragma unroll
            for (int c = 0; c < 2; ++c) {
                int ct = wv + 12 * c;
                if (ct >= 19) break;
                acc[rt][c] = __builtin_amdgcn_mfma_f32_16x16x32_bf16(a, bb[c], acc[rt][c], 0, 0, 0);
            }
        }
        #pragma unroll
        for (int c = 0; c < 2; ++c) {
            int ct = wv + 12 * c;
            if (ct < 19)
                bb[c] = *(const bf16x8v*)&whi[((unsigned)(kt * 19 + ct) * 64u + lane) * 8u];
        }
        #pragma unroll
        for (int rt = 0; rt < 4; ++rt) {
            bf16x8v a = *(const bf16x8v*)&As[(rt * 16 + cr) * LDK + kt * 32 + quad * 8];
            #pragma unroll
            for (int c = 0; c < 2; ++c) {
                int ct = wv + 12 * c;
                if (ct >= 19) break;
                acc[rt][c] = __builtin_amdgcn_mfma_f32_16x16x32_bf16(a, bb[c], acc[rt][c], 0, 0, 0);
            }
        }
    }
    __syncthreads();
    #pragma unroll
    for (int c = 0; c < 2; ++c) {
        int ct = wv + 12 * c;
        if (ct >= 19) break;
        int col = ct * 16 + cr;
        if (col >= 300) continue;
        #pragma unroll
        for (int rt = 0; rt < 4; ++rt)
            #pragma unroll
            for (int r = 0; r < 4; ++r) {
                float v = acc[rt][c][r];
                As[(rt * 16 + quad * 4 + r) * LDK + col] = f2bf_us(RELU ? fmaxf(v, 0.f) : v);
            }
    }
    __syncthreads();
    for (int idx = tid; idx < 64 * 75; idx += 768) {
        int r = idx / 75, q = idx - r * 75;
        *(ushort4*)&out_rows[(unsigned)(n0 + r) * 300u + q * 4] = *(const ushort4*)&As[r * LDK + q * 4];
    }
}

// ---------------- mp GEMM: h[e] = relu(h[e] + (inc[src[e]] - h[rev(e)]) @ W + b) ----------------
// r9 tee + r11 16B stage: 37 16B-groups (cols 0-295) + tail. Hs rows 656B (16-aligned),
// Hs2 restrided to 304 ushorts (608B, 16-aligned) so the raw tee is one 16B LDS store.
__global__ __launch_bounds__(768, 6) void k_mp_mfma(
        unsigned short* __restrict__ h, const unsigned short* __restrict__ inc,
        const int* __restrict__ srcH, const int* __restrict__ dstH,
        const unsigned short* __restrict__ whi, const unsigned short* __restrict__ wlo,
        const float* __restrict__ bias) {
    constexpr int LDK = 328;
    __shared__ __align__(16) unsigned short Hs[64 * LDK];
    __shared__ __align__(16) unsigned short Hs2[64 * 304];   // own-row h, teed during stage
    __shared__ int ssrc[64];
    const int tid = threadIdx.x;
    const int lane = tid & 63, wv = tid >> 6;
    const int quad = lane >> 4, cr = lane & 15;
    const int p0 = blockIdx.x * 32;
    if (tid < 64) {
        int r = tid;
        int e = (r < 32) ? (p0 + r) : (p0 + r - 32 + HALF);
        int s = (e < HALF) ? srcH[e] : dstH[e - HALF];
        ssrc[r] = clampi(s, 0, NN - 1);
    }
    __syncthreads();
    // 16B operand staging: cols 0-295
    for (int idx = tid; idx < 64 * 37; idx += 768) {
        int r = idx / 37, q = idx - r * 37;
        int col = q * 8;
        unsigned ep = (r < 32) ? (unsigned)(p0 + r + HALF) : (unsigned)(p0 + r - 32);
        uint4 hraw = *(const uint4*)&h[ep * 300u + col];
        uint4 iraw = *(const uint4*)&inc[(unsigned)ssrc[r] * 300u + col];
        float hf[8], inf[8], of[8];
        bf8_to_f(hraw, hf);
        bf8_to_f(iraw, inf);
        #pragma unroll
        for (int i = 0; i < 8; ++i) of[i] = inf[i] - hf[i];
        *(uint4*)&Hs[r * LDK + col] = f8_to_bf(of);
        *(uint4*)&Hs2[(r ^ 32) * 304 + col] = hraw;
    }
    // tail: cols 296-299 real, 300-319 zero pad
    for (int idx = tid; idx < 64; idx += 768) {
        int r = idx;
        unsigned ep = (r < 32) ? (unsigned)(p0 + r + HALF) : (unsigned)(p0 + r - 32);
        ushort4 hu = *(const ushort4*)&h[ep * 300u + 296];
        float4 hp = make_float4(bf2f_us(hu.x), bf2f_us(hu.y), bf2f_us(hu.z), bf2f_us(hu.w));
        float4 iv = ld4(&inc[(unsigned)ssrc[r] * 300u + 296]);
        st4(&Hs[r * LDK + 296],
            make_float4(iv.x - hp.x, iv.y - hp.y, iv.z - hp.z, iv.w - hp.w));
        *(ushort4*)&Hs2[(r ^ 32) * 304 + 296] = hu;
        #pragma unroll
        for (int k = 300; k < 320; k += 4)
            *(ushort4*)&Hs[r * LDK + k] = make_ushort4(0, 0, 0, 0);
    }
    __syncthreads();
    f32x4v acc[4][2];
    #pragma unroll
    for (int c = 0; c < 2; ++c)
        #pragma unroll
        for (int rt = 0; rt < 4; ++rt) {
            f32x4v a = {0.f, 0.f, 0.f, 0.f};
            acc[rt][c] = a;
        }
    for (int kt = 0; kt < 10; ++kt) {
        bf16x8v bb[2];
        #pragma unroll
        for (int c = 0; c < 2; ++c) {
            int ct = wv + 12 * c;
            if (ct < 19)
                bb[c] = *(const bf16x8v*)&wlo[((unsigned)(kt * 19 + ct) * 64u + lane) * 8u];
        }
        #pragma unroll
        for (int rt = 0; rt < 4; ++rt) {
            bf16x8v a = *(const bf16x8v*)&Hs[(rt * 16 + cr) * LDK + kt * 32 + quad * 8];
            #pragma unroll
            for (int c = 0; c < 2; ++c) {
                int ct = wv + 12 * c;
                if (ct >= 19) break;
                acc[rt][c] = __builtin_amdgcn_mfma_f32_16x16x32_bf16(a, bb[c], acc[rt][c], 0, 0, 0);
            }
        }
        #pragma unroll
        for (int c = 0; c < 2; ++c) {
            int ct = wv + 12 * c;
            if (ct < 19)
                bb[c] = *(const bf16x8v*)&whi[((unsigned)(kt * 19 + ct) * 64u + lane) * 8u];
        }
        #pragma unroll
        for (int rt = 0; rt < 4; ++rt) {
            bf16x8v a = *(const bf16x8v*)&Hs[(rt * 16 + cr) * LDK + kt * 32 + quad * 8];
            #pragma unroll
            for (int c = 0; c < 2; ++c) {
                int ct = wv + 12 * c;
                if (ct >= 19) break;
                acc[rt][c] = __builtin_amdgcn_mfma_f32_16x16x32_bf16(a, bb[c], acc[rt][c], 0, 0, 0);
            }
        }
    }
    __syncthreads();   // all GEMM reads of Hs done before epilogue overwrites
    #pragma unroll
    for (int c = 0; c < 2; ++c) {
        int ct = wv + 12 * c;
        if (ct >= 19) break;
        int col = ct * 16 + cr;
        if (col >= 300) continue;
        float bv = bias[col];
        #pragma unroll
        for (int rt = 0; rt < 4; ++rt)
            #pragma unroll
            for (int r = 0; r < 4; ++r) {
                int row = rt * 16 + quad * 4 + r;
                float hv = bf2f_us(Hs2[row * 304 + col]);   // own-row h from LDS
                Hs[row * LDK + col] = f2bf_us(fmaxf(acc[rt][c][r] + bv + hv, 0.f));
            }
    }
    __syncthreads();
    for (int idx = tid; idx < 64 * 75; idx += 768) {
        int r = idx / 75, q = idx - r * 75;
        unsigned e = (r < 32) ? (unsigned)(p0 + r) : (unsigned)(p0 + r - 32 + HALF);
        *(ushort4*)&h[e * 300u + q * 4] = *(const ushort4*)&Hs[r * LDK + q * 4];
    }
}

// ---------------- pooling (bf16 rows, 2x unrolled sequential adds) + reparam ----------------
__global__ __launch_bounds__(320) void k_pool(const unsigned short* __restrict__ rows,
                                              const float* __restrict__ wat,
                                              const int* __restrict__ gs, float* __restrict__ outg) {
    int g = blockIdx.x, c = threadIdx.x;
    if (c >= 300) return;
    int lo = clampi(gs[g], 0, NN), hi = clampi(gs[g + 1], 0, NN);
    float acc = 0.f;
    int n = lo;
    for (; n + 2 <= hi; n += 2) {
        float v0 = bf2f_us(rows[(unsigned)n * 300u + c]) * wat[n];
        float v1 = bf2f_us(rows[(unsigned)(n + 1) * 300u + c]) * wat[n + 1];
        acc += v0;           // sequential adds: identical order to the scalar loop
        acc += v1;
    }
    if (n < hi)
        acc += bf2f_us(rows[(unsigned)n * 300u + c]) * wat[n];
    float cn = fmaxf((float)(hi - lo), 1.f);
    outg[g * 300 + c] = acc / cn;
}
__global__ __launch_bounds__(320) void k_final(const float* __restrict__ mu_g, const float* __restrict__ lv_g,
                                               const float* __restrict__ eps, float* __restrict__ out) {
    int g = blockIdx.x, c = threadIdx.x;
    if (c >= 300) return;
    out[g * 300 + c] = mu_g[g * 300 + c] + expf(0.5f * lv_g[g * 300 + c]) * eps[g * 300 + c];
}

extern "C" void kernel_launch(void* const* d_in, const int* in_sizes, int n_in,
                              void* d_out, int out_size, void* d_ws, size_t ws_size,
                              hipStream_t stream) {
    float* outp = (float*)d_out;

    const size_t NEED = 199500000ull;   // carve ~199.43 MB; ws proven >= 200,000,000
    if (ws_size < NEED) {
        k_zerof<<<(out_size + 255) / 256, 256, 0, stream>>>(outp, out_size);
        return;
    }

    const float* x   = (const float*)d_in[0];
    const float* ea  = (const float*)d_in[1];
    const float* wat = (const float*)d_in[2];
    const float* eps = (const float*)d_in[3];
    const int* srcH  = (const int*)d_in[4];
    const int* dstH  = (const int*)d_in[5];
    const int* batch = (const int*)d_in[6];
    const float* w_t_lin  = (const float*)d_in[7];
    const float* b_t_lin  = (const float*)d_in[8];
    const float* w_t_mp   = (const float*)d_in[9];
    const float* b_t_mp   = (const float*)d_in[10];
    const float* w_t_au   = (const float*)d_in[11];
    const float* b_t_au   = (const float*)d_in[12];
    const float* w_mu_lin = (const float*)d_in[13];
    const float* b_mu_lin = (const float*)d_in[14];
    const float* w_mu_mp  = (const float*)d_in[15];
    const float* b_mu_mp  = (const float*)d_in[16];
    const float* w_mu_au  = (const float*)d_in[17];
    const float* b_mu_au  = (const float*)d_in[18];
    const float* w_lv_lin = (const float*)d_in[19];
    const float* b_lv_lin = (const float*)d_in[20];
    const float* w_lv_mp  = (const float*)d_in[21];
    const float* b_lv_mp  = (const float*)d_in[22];
    const float* w_lv_au  = (const float*)d_in[23];
    const float* b_lv_au  = (const float*)d_in[24];

    char* p = (char*)d_ws;
    auto alloc = [&](size_t nbytes) { char* q = p; p += (nbytes + 255) & ~(size_t)255; return q; };
    unsigned short* h   = (unsigned short*)alloc((size_t)NE * 300 * 2);   // 96 MB
    unsigned short* inc = (unsigned short*)alloc((size_t)NN * 300 * 2);   // 48 MB (segsum result)
    unsigned short* sh  = (unsigned short*)alloc((size_t)NN * 300 * 2);   // 48 MB
    const size_t MPU = (size_t)3 * 10 * 19 * 512;   // mp tables (ushorts)
    unsigned short* wh_mp = (unsigned short*)alloc(MPU * 2);
    unsigned short* wl_mp = (unsigned short*)alloc(MPU * 2);
    const size_t LAU = (size_t)29 * 19 * 512;       // lin+au tables
    unsigned short* wh_la = (unsigned short*)alloc(LAU * 2);
    unsigned short* wl_la = (unsigned short*)alloc(LAU * 2);
    float* mu_g = (float*)alloc((size_t)NG * 300 * 4);
    float* lv_g = (float*)alloc((size_t)NG * 300 * 4);
    int* deg    = (int*)alloc(NN * 4);               // reused as cursor (alias-safe)
    int* startA = (int*)alloc((NN + 1) * 4);
    int* elist  = (int*)alloc(NE * 4);
    int* degg   = (int*)alloc(NG * 4);
    int* gs     = (int*)alloc((NG + 1) * 4);
    int* part   = (int*)alloc(SCB * 4);

    // ---- CSR (incoming by dst), multi-block scan; cursor aliases deg ----
    k_zeroi<<<(NN + 255) / 256, 256, 0, stream>>>(deg, NN);
    k_hist<<<(NE + 255) / 256, 256, 0, stream>>>(srcH, dstH, deg);
    k_scan_part<<<SCB, 256, 0, stream>>>(deg, part, NN);
    k_scan_offsets<<<1, 256, 0, stream>>>(part);
    k_scan_apply<<<SCB, 256, 0, stream>>>(deg, part, startA, deg, NN);
    k_fill<<<(NE + 255) / 256, 256, 0, stream>>>(srcH, dstH, deg, elist);
    // ---- graph-CSR over sorted batch ----
    k_zeroi<<<(NG + 255) / 256, 256, 0, stream>>>(degg, NG);
    k_histg<<<(NN + 255) / 256, 256, 0, stream>>>(batch, degg);
    k_scan_part<<<SCB, 256, 0, stream>>>(degg, part, NG);
    k_scan_offsets<<<1, 256, 0, stream>>>(part);
    k_scan_apply<<<SCB, 256, 0, stream>>>(degg, part, gs, (int*)nullptr, NG);

    const int SSG = (NN * 38 + 255) / 256;
    const size_t MP_L = (size_t)10 * 19 * 512;      // ushorts per mp layer
    auto wsplit_conv = [&](const float* Wmp, const float* Wlin, int Klin, int nktlin,
                           const float* Wau, int Kau, int nktau) {
        int total = 570 + nktlin * 19 + nktau * 19;
        k_wsplit_conv<<<(total * 64 + 255) / 256, 256, 0, stream>>>(
            Wmp, Wlin, Klin, nktlin, Wau, Kau, nktau, wh_mp, wl_mp, wh_la, wl_la);
    };

    // ================= conv t =================
    wsplit_conv(w_t_mp, w_t_lin, 147, 5, w_t_au, 433, 14);
    const size_t AU_T = (size_t)5 * 19 * 512;
    k_lin_mfma<133, float><<<NE / 64, 768, 0, stream>>>(x, ea, srcH, dstH, wh_la, wl_la, b_t_lin, h);
    for (int i = 0; i < 3; ++i) {
        k_segsum8<<<SSG, 256, 0, stream>>>(h, elist, startA, inc);
        k_mp_mfma<<<HALF / 32, 768, 0, stream>>>(h, inc, srcH, dstH,
                                                 wh_mp + i * MP_L, wl_mp + i * MP_L, b_t_mp + i * 300);
    }
    // de-fused au: segsum first (streaming, roofline), then fully dense au GEMM
    k_segsum8<<<SSG, 256, 0, stream>>>(h, elist, startA, inc);
    k_au_mfma<133, float, true><<<NN / 64, 768, 0, stream>>>(x, inc,
                                                             wh_la + AU_T, wl_la + AU_T, b_t_au, sh);

    // ================= conv mu =================
    wsplit_conv(w_mu_mp, w_mu_lin, 314, 10, w_mu_au, 600, 19);
    const size_t AU_MU = (size_t)10 * 19 * 512;
    k_lin_mfma<300, unsigned short><<<NE / 64, 768, 0, stream>>>(sh, ea, srcH, dstH, wh_la, wl_la, b_mu_lin, h);
    for (int i = 0; i < 3; ++i) {
        k_segsum8<<<SSG, 256, 0, stream>>>(h, elist, startA, inc);
        k_mp_mfma<<<HALF / 32, 768, 0, stream>>>(h, inc, srcH, dstH,
                                                 wh_mp + i * MP_L, wl_mp + i * MP_L, b_mu_mp + i * 300);
    }
    // de-fused au: after this segsum, h is DEAD (au reads only sh + inc) -> au output
    // lives in the h buffer's first 48 MB; pool consumes it before lv's lin rewrites h.
    k_segsum8<<<SSG, 256, 0, stream>>>(h, elist, startA, inc);
    {
        unsigned short* rows = h;
        k_au_mfma<300, unsigned short, false><<<NN / 64, 768, 0, stream>>>(sh, inc,
                                                                           wh_la + AU_MU, wl_la + AU_MU, b_mu_au, rows);
        k_pool<<<NG, 320, 0, stream>>>(rows, wat, gs, mu_g);
    }

    // ================= conv lv =================
    wsplit_conv(w_lv_mp, w_lv_lin, 314, 10, w_lv_au, 600, 19);
    k_lin_mfma<300, unsigned short><<<NE / 64, 768, 0, stream>>>(sh, ea, srcH, dstH, wh_la, wl_la, b_lv_lin, h);
    for (int i = 0; i < 3; ++i) {
        k_segsum8<<<SSG, 256, 0, stream>>>(h, elist, startA, inc);
        k_mp_mfma<<<HALF / 32, 768, 0, stream>>>(h, inc, srcH, dstH,
                                                 wh_mp + i * MP_L, wl_mp + i * MP_L, b_lv_mp + i * 300);
    }
    k_segsum8<<<SSG, 256, 0, stream>>>(h, elist, startA, inc);
    {
        unsigned short* rows = h;
        k_au_mfma<300, unsigned short, false><<<NN / 64, 768, 0, stream>>>(sh, inc,
                                                                           wh_la + AU_MU, wl_la + AU_MU, b_lv_au, rows);
        k_pool<<<NG, 320, 0, stream>>>(rows, wat, gs, lv_g);
    }

    // ---- reparam ----
    k_final<<<NG, 320, 0, stream>>>(mu_g, lv_g, eps, outp);
}